// Round 3
// baseline (200.456 us; speedup 1.0000x reference)
//
#include <hip/hip_runtime.h>
#include <math.h>

// FactorMuE: profile-HMM forward log-likelihood.
// Dims (static): M=128, Mp1=129, K=258, D=21, ZD=64, B=64, L=256, P=774.
// Key reference-fidelity detail: row k=128 of the transition matrix is all
// NEG=-1e32; the reference's float32 row-lse absorbs log(258), so the
// normalized row is 0.0 -> linear outflow weight 1.0 PER DESTINATION.
#define MP1 129
#define KK  258
#define DD  21
#define ZDIM 64
#define BB  64
#define LL  256
#define EROW 260   // E row: match m at col m (0..128), 129 unused, insert m at 130+m, pad 259
#define ETOK 22    // 21 tokens + ones row (index 21 = missing)

// ---------------- ws layout (floats) ----------------
#define OFF_TOK  366080
#define OFF_COEF 382464
#define C_UU   0
#define C_DXM  258
#define C_DXI  516
#define C_WM   774
#define C_WI   903
#define C_DMID 1032
#define C_PI0  1160

// -------- emission: latent = z@W^T + b, *softplus(it), softmax over D --------
__global__ __launch_bounds__(64) void k_emis(const float* __restrict__ z,
                                             const float* __restrict__ W,
                                             const float* __restrict__ bias,
                                             const float* __restrict__ invt,
                                             float* __restrict__ E) {
    int lane = threadIdx.x;
    int half = lane >> 5;
    int d    = lane & 31;
    int row  = blockIdx.x * 2 + half;          // [0, 16512)
    int b    = row / (2 * MP1);
    int rem  = row % (2 * MP1);
    int c    = rem / MP1;
    int m    = rem % MP1;
    float it = log1pf(expf(invt[0]));          // softplus
    float v  = -INFINITY;
    if (d < DD) {
        int od = (c * MP1 + m) * DD + d;
        const float4* zr = (const float4*)(z + (size_t)b * ZDIM);
        const float4* wr = (const float4*)(W + (size_t)od * ZDIM);
        float acc = bias[od];
        #pragma unroll
        for (int j = 0; j < ZDIM / 4; ++j) {
            float4 a = zr[j], w = wr[j];
            acc += a.x * w.x + a.y * w.y + a.z * w.z + a.w * w.w;
        }
        v = acc * it;
    }
    float mx = v;
    #pragma unroll
    for (int off = 16; off >= 1; off >>= 1) mx = fmaxf(mx, __shfl_xor(mx, off, 32));
    float p = (d < DD) ? expf(v - mx) : 0.f;
    float s = p;
    #pragma unroll
    for (int off = 16; off >= 1; off >>= 1) s += __shfl_xor(s, off, 32);
    int col = (c == 0) ? m : (130 + m);
    float* Eb = E + (size_t)b * ETOK * EROW;
    if (d < DD)  Eb[d * EROW + col] = p / s;   // exp(log-softmax)
    if (d == DD) Eb[DD * EROW + col] = 1.0f;   // ones row for missing steps
}

// -------- token extraction: data is one_hot*mask, exact 0/1 --------
__global__ void k_tok(const float* __restrict__ data, int* __restrict__ tok) {
    int i = blockIdx.x * blockDim.x + threadIdx.x;   // b*LL + l
    if (i >= BB * LL) return;
    const float* r = data + (size_t)i * DD;
    int idx = DD; float ssum = 0.f;
    for (int d = 0; d < DD; ++d) { float v = r[d]; ssum += v; if (v > 0.5f) idx = d; }
    tok[i] = (ssum > 0.5f) ? idx : DD;
}

// -------- transition coefficients (single block) --------
__global__ __launch_bounds__(256) void k_trans(const float* __restrict__ ins,
                                               const float* __restrict__ del,
                                               float* __restrict__ coef) {
    __shared__ float il[774], dl[774], Smid[129];
    int t = threadIdx.x;
    for (int p = t; p < 387; p += 256) {
        float x0 = ins[2 * p], x1 = ins[2 * p + 1];
        float mx = fmaxf(x0, x1);
        float ls = mx + logf(expf(x0 - mx) + expf(x1 - mx));
        il[2 * p] = x0 - ls; il[2 * p + 1] = x1 - ls;
        float y0 = del[2 * p], y1 = del[2 * p + 1];
        float my = fmaxf(y0, y1);
        float lt = my + logf(expf(y0 - my) + expf(y1 - my));
        dl[2 * p] = y0 - lt; dl[2 * p + 1] = y1 - lt;
    }
    __syncthreads();
    if (t == 0) {
        Smid[0] = 0.f;
        for (int mm = 1; mm <= 128; ++mm)
            Smid[mm] = Smid[mm - 1] + il[(mm * 3 + 2) * 2 + 0] + dl[(mm * 3 + 2) * 2 + 1];
    }
    __syncthreads();
    float* uu  = coef + C_UU;
    float* dxM = coef + C_DXM;
    float* dxI = coef + C_DXI;
    float* wM  = coef + C_WM;
    float* wI  = coef + C_WI;
    float* dmd = coef + C_DMID;
    float* pi0 = coef + C_PI0;
    for (int k = t; k < KK; k += 256) {
        if (k == 128) { uu[k] = 0.f; dxM[k] = 0.f; dxI[k] = 0.f; continue; }
        int g  = (k < MP1) ? 0 : 1;
        int n0 = g ? (k - MP1) : (k + 1);
        float i0 = il[(n0 * 3 + g) * 2 + 0], i1 = il[(n0 * 3 + g) * 2 + 1];
        float e0 = dl[(n0 * 3 + g) * 2 + 0], e1 = dl[(n0 * 3 + g) * 2 + 1];
        float diagM = i0 + e0;
        float diagI = i1;
        float src   = i0 + e1;
        float mx = diagM, s = 1.f;
        { float e = diagI; if (e > mx) { s = s * expf(mx - e) + 1.f; mx = e; } else s += expf(e - mx); }
        for (int mp = n0 + 1; mp <= 128; ++mp) {
            float base = src + Smid[mp - 1] - Smid[n0];
            float eM = base + il[(mp * 3 + 2) * 2 + 0] + dl[(mp * 3 + 2) * 2 + 0];
            float eI = base + il[(mp * 3 + 2) * 2 + 1];
            if (eM > mx) { s = s * expf(mx - eM) + 1.f; mx = eM; } else s += expf(eM - mx);
            if (eI > mx) { s = s * expf(mx - eI) + 1.f; mx = eI; } else s += expf(eI - mx);
        }
        float lse = mx + logf(s);
        uu[k]  = expf(src - lse);
        dxM[k] = expf(diagM - lse);
        dxI[k] = expf(diagI - lse);
    }
    for (int mp = t; mp < MP1; mp += 256) {
        wM[mp] = expf(il[(mp * 3 + 2) * 2 + 0] + dl[(mp * 3 + 2) * 2 + 0]);
        wI[mp] = expf(il[(mp * 3 + 2) * 2 + 1]);
    }
    for (int tt = t; tt < 128; tt += 256)
        dmd[tt] = (tt == 0) ? 1.f : expf(il[(tt * 3 + 2) * 2 + 0] + dl[(tt * 3 + 2) * 2 + 1]);
    __syncthreads();
    if (t == 0) {
        float i00 = il[0], i01 = il[1], d00 = dl[0], d01 = dl[1];
        float a0[KK];
        a0[0]   = i00 + d00;
        a0[129] = i01;
        for (int mp = 1; mp <= 128; ++mp) {
            float base = i00 + d01 + Smid[mp - 1];
            a0[mp]       = base + il[(mp * 3 + 2) * 2 + 0] + dl[(mp * 3 + 2) * 2 + 0];
            a0[129 + mp] = base + il[(mp * 3 + 2) * 2 + 1];
        }
        float mx = -INFINITY;
        for (int i = 0; i < KK; ++i) mx = fmaxf(mx, a0[i]);
        float s = 0.f;
        for (int i = 0; i < KK; ++i) s += expf(a0[i] - mx);
        float lse = mx + logf(s);
        for (int i = 0; i < KK; ++i) pi0[i] = expf(a0[i] - lse);
    }
}

// -------- forward scan: one wave per batch, alpha in registers, O(K) per step --------
__global__ __launch_bounds__(64) void k_fwd(const float* __restrict__ Eg,
                                            const int* __restrict__ tokg,
                                            const float* __restrict__ coef,
                                            float* __restrict__ out) {
    const float* uu  = coef + C_UU;
    const float* dxM = coef + C_DXM;
    const float* dxI = coef + C_DXI;
    const float* wMg = coef + C_WM;
    const float* wIg = coef + C_WI;
    const float* dmd = coef + C_DMID;
    const float* pi0 = coef + C_PI0;
    __shared__ float E[ETOK * EROW];
    __shared__ int tok[LL];
    int lane = threadIdx.x;
    int b = blockIdx.x;
    const float4* s4 = (const float4*)(Eg + (size_t)b * ETOK * EROW);
    float4* d4 = (float4*)E;
    for (int i = lane; i < ETOK * EROW / 4; i += 64) d4[i] = s4[i];
    ((int4*)tok)[lane] = ((const int4*)(tokg + b * LL))[lane];
    __syncthreads();

    int m0 = 2 * lane, m1 = 2 * lane + 1;
    bool L0 = (lane == 0), L63 = (lane == 63);
    float f63 = L63 ? 1.f : 0.f;
    float cM0 = L0 ? 0.f : uu[m0 - 1];
    float cI0 = uu[129 + m0];
    float cM1 = uu[m0];
    float cI1 = uu[129 + m1];
    float d0 = dmd[m0], d1v = dmd[m1];
    float Apair = d0 * d1v;
    float wM0 = wMg[m0], wM1 = wMg[m1], wI0 = wIg[m0], wI1 = wIg[m1];
    float xMA0 = L0 ? 0.f : dxM[m0 - 1], xIA0 = L0 ? 0.f : dxI[m0 - 1];
    float xMB0 = dxM[129 + m0], xIB0 = dxI[129 + m0];
    float xMA1 = dxM[m0], xIA1 = dxI[m0];
    float xMB1 = dxM[129 + m1], xIB1 = dxI[129 + m1];
    float wM2 = L63 ? wMg[128] : 0.f, wI2 = L63 ? wIg[128] : 0.f;
    float xMA2 = L63 ? dxM[127] : 0.f, xIA2 = L63 ? dxI[127] : 0.f;
    float xMB2 = L63 ? dxM[257] : 0.f, xIB2 = L63 ? dxI[257] : 0.f;

    int tk = tok[0];
    const float* Er = E + tk * EROW;
    float aM0 = pi0[m0] * Er[m0];
    float aM1 = pi0[m1] * Er[m1];
    float aI0 = pi0[129 + m0] * Er[130 + m0];
    float aI1 = pi0[129 + m1] * Er[130 + m1];
    float aM2 = f63 * pi0[128] * Er[128];
    float aI2 = f63 * pi0[257] * Er[258];

    float logZ = 0.f;
    float part = aM0 + aM1 + aI0 + aI1 + aM2 + aI2;

    for (int l = 1; l < LL; ++l) {
        tk = tok[l];
        const float* Err = E + tk * EROW;
        float EM0 = Err[m0], EM1 = Err[m1];
        float EI0 = Err[130 + m0], EI1 = Err[130 + m1];
        float EM2 = Err[128], EI2 = Err[258];
        // rescale using previous step's sum (independent of this step's scan)
        float s = part;
        #pragma unroll
        for (int off = 1; off < 64; off <<= 1) s += __shfl_xor(s, off);
        float invs = 1.0f / s;
        logZ += logf(s);
        // neighbor alpha + forbidden-row broadcast.
        // Reference float32 absorption: row 128 normalizes to 0.0 logits ->
        // linear weight 1.0 to EVERY destination (not 1/258).
        float aMp  = __shfl_up(aM1, 1);
        float u128 = __shfl(aM2, 63);
        float r0 = fmaf(aMp, cM0, aI0 * cI0);
        float r1 = fmaf(aM0, cM1, aI1 * cI1);
        float A = Apair;
        float B = fmaf(d1v, r0, r1);
        #pragma unroll
        for (int off = 1; off < 64; off <<= 1) {
            float An = __shfl_up(A, off);
            float Bn = __shfl_up(B, off);
            if (lane >= off) { B = fmaf(A, Bn, B); A *= An; }
        }
        float Bex = __shfl_up(B, 1);
        float G0 = L0 ? 0.f : Bex;       // G[m0]
        float G1 = fmaf(d0, G0, r0);     // G[m1]
        float G2 = B;                    // lane63: G[128]
        float mM0 = wM0 * G0 + xMA0 * aMp + xMB0 * aI0 + u128;
        float mI0 = wI0 * G0 + xIA0 * aMp + xIB0 * aI0 + u128;
        float mM1 = wM1 * G1 + xMA1 * aM0 + xMB1 * aI1 + u128;
        float mI1 = wI1 * G1 + xIA1 * aM0 + xIB1 * aI1 + u128;
        float mM2 = wM2 * G2 + xMA2 * aM1 + xMB2 * aI2 + u128;
        float mI2 = wI2 * G2 + xIA2 * aM1 + xIB2 * aI2 + u128;
        aM0 = mM0 * EM0 * invs;
        aM1 = mM1 * EM1 * invs;
        aI0 = mI0 * EI0 * invs;
        aI1 = mI1 * EI1 * invs;
        aM2 = mM2 * EM2 * invs * f63;
        aI2 = mI2 * EI2 * invs * f63;
        part = aM0 + aM1 + aI0 + aI1 + aM2 + aI2;
    }
    float s = part;
    #pragma unroll
    for (int off = 1; off < 64; off <<= 1) s += __shfl_xor(s, off);
    if (lane == 0) out[b] = logZ + logf(s);
}

extern "C" void kernel_launch(void* const* d_in, const int* in_sizes, int n_in,
                              void* d_out, int out_size, void* d_ws, size_t ws_size,
                              hipStream_t stream) {
    const float* data  = (const float*)d_in[0];
    const float* z     = (const float*)d_in[1];
    const float* dec_W = (const float*)d_in[2];
    const float* dec_b = (const float*)d_in[3];
    const float* ins   = (const float*)d_in[4];
    const float* del   = (const float*)d_in[5];
    const float* invt  = (const float*)d_in[6];
    float* out = (float*)d_out;

    float* ws   = (float*)d_ws;
    float* E    = ws;
    int*   tok  = (int*)(ws + OFF_TOK);
    float* coef = ws + OFF_COEF;

    k_emis<<<BB * 2 * MP1 / 2, 64, 0, stream>>>(z, dec_W, dec_b, invt, E);
    k_tok<<<(BB * LL + 255) / 256, 256, 0, stream>>>(data, tok);
    k_trans<<<1, 256, 0, stream>>>(ins, del, coef);
    k_fwd<<<BB, 64, 0, stream>>>(E, tok, coef, out);
}

// Round 4
// 122.654 us; speedup vs baseline: 1.6343x; 1.6343x over previous
//
#include <hip/hip_runtime.h>
#include <math.h>

// FactorMuE: profile-HMM forward log-likelihood.
// Dims (static): M=128, Mp1=129, K=258, D=21, ZD=64, B=64, L=256, P=774.
// Reference-fidelity detail: row k=128 of the transition matrix is all
// NEG=-1e32; the reference's float32 row-lse absorbs log(258), so the
// normalized row is 0.0 -> linear outflow weight 1.0 PER DESTINATION.
#define MP1 129
#define KK  258
#define DD  21
#define ZDIM 64
#define BB  64
#define LL  256
#define EROW 260   // E row: match m at col m (0..128), 129 unused, insert m at 130+m, pad 259
#define ETOK 22    // 21 tokens + ones row (index 21 = missing)

// ---------------- ws layout (floats) ----------------
#define OFF_TOK  366080
#define OFF_COEF 382464
#define C_UU   0
#define C_DXM  258
#define C_DXI  516
#define C_WM   774
#define C_WI   903
#define C_DMID 1032
#define C_PI0  1160

// -------- DPP helpers (cross-lane on the VALU pipe, not the DS pipe) --------
// update_dpp(old, src, ctrl, row_mask, bank_mask, bound_ctrl=false):
// invalid/masked lanes keep `old` (we pass the combine identity).
template <int CTRL, int RM, int BM>
__device__ __forceinline__ float updpp(float old, float src) {
    return __int_as_float(__builtin_amdgcn_update_dpp(
        __float_as_int(old), __float_as_int(src), CTRL, RM, BM, false));
}
__device__ __forceinline__ float readlane_f(float v, int lane) {
    return __int_as_float(__builtin_amdgcn_readlane(__float_as_int(v), lane));
}
// full-wave sum, result valid in lane 63 (scan-style reduction)
__device__ __forceinline__ float wave_sum_to63(float s) {
    s += updpp<0x111, 0xf, 0xf>(0.f, s);   // row_shr:1
    s += updpp<0x112, 0xf, 0xf>(0.f, s);   // row_shr:2
    s += updpp<0x114, 0xf, 0xf>(0.f, s);   // row_shr:4
    s += updpp<0x118, 0xf, 0xf>(0.f, s);   // row_shr:8
    s += updpp<0x142, 0xa, 0xf>(0.f, s);   // row_bcast:15 -> rows 1,3
    s += updpp<0x143, 0xc, 0xf>(0.f, s);   // row_bcast:31 -> rows 2,3
    return s;
}

// -------- emission: latent = z@W^T + b, *softplus(it), softmax over D --------
__global__ __launch_bounds__(64) void k_emis(const float* __restrict__ z,
                                             const float* __restrict__ W,
                                             const float* __restrict__ bias,
                                             const float* __restrict__ invt,
                                             float* __restrict__ E) {
    int lane = threadIdx.x;
    int half = lane >> 5;
    int d    = lane & 31;
    int row  = blockIdx.x * 2 + half;          // [0, 16512)
    int b    = row / (2 * MP1);
    int rem  = row % (2 * MP1);
    int c    = rem / MP1;
    int m    = rem % MP1;
    float it = log1pf(expf(invt[0]));          // softplus
    float v  = -INFINITY;
    if (d < DD) {
        int od = (c * MP1 + m) * DD + d;
        const float4* zr = (const float4*)(z + (size_t)b * ZDIM);
        const float4* wr = (const float4*)(W + (size_t)od * ZDIM);
        float acc = bias[od];
        #pragma unroll
        for (int j = 0; j < ZDIM / 4; ++j) {
            float4 a = zr[j], w = wr[j];
            acc += a.x * w.x + a.y * w.y + a.z * w.z + a.w * w.w;
        }
        v = acc * it;
    }
    float mx = v;
    #pragma unroll
    for (int off = 16; off >= 1; off >>= 1) mx = fmaxf(mx, __shfl_xor(mx, off, 32));
    float p = (d < DD) ? expf(v - mx) : 0.f;
    float s = p;
    #pragma unroll
    for (int off = 16; off >= 1; off >>= 1) s += __shfl_xor(s, off, 32);
    int col = (c == 0) ? m : (130 + m);
    float* Eb = E + (size_t)b * ETOK * EROW;
    if (d < DD)  Eb[d * EROW + col] = p / s;   // exp(log-softmax)
    if (d == DD) Eb[DD * EROW + col] = 1.0f;   // ones row for missing steps
}

// -------- token extraction: data is one_hot*mask, exact 0/1 --------
__global__ void k_tok(const float* __restrict__ data, int* __restrict__ tok) {
    int i = blockIdx.x * blockDim.x + threadIdx.x;   // b*LL + l
    if (i >= BB * LL) return;
    const float* r = data + (size_t)i * DD;
    int idx = DD; float ssum = 0.f;
    for (int d = 0; d < DD; ++d) { float v = r[d]; ssum += v; if (v > 0.5f) idx = d; }
    tok[i] = (ssum > 0.5f) ? idx : DD;
}

// -------- transition coefficients (single block, no scratch arrays) --------
__global__ __launch_bounds__(320) void k_trans(const float* __restrict__ ins,
                                               const float* __restrict__ del,
                                               float* __restrict__ coef) {
    __shared__ float il[774], dl[774], Smid[129];
    int t = threadIdx.x;
    for (int p = t; p < 387; p += 320) {
        float x0 = ins[2 * p], x1 = ins[2 * p + 1];
        float mx = fmaxf(x0, x1);
        float ls = mx + logf(expf(x0 - mx) + expf(x1 - mx));
        il[2 * p] = x0 - ls; il[2 * p + 1] = x1 - ls;
        float y0 = del[2 * p], y1 = del[2 * p + 1];
        float my = fmaxf(y0, y1);
        float lt = my + logf(expf(y0 - my) + expf(y1 - my));
        dl[2 * p] = y0 - lt; dl[2 * p + 1] = y1 - lt;
    }
    __syncthreads();
    // Smid prefix sum (128 terms) by wave 0: 2 values/lane + shfl scan
    if (t < 64) {
        int mmA = 1 + 2 * t, mmB = 2 + 2 * t;          // 1..127 / 2..128
        float xA = il[(mmA * 3 + 2) * 2 + 0] + dl[(mmA * 3 + 2) * 2 + 1];
        float xB = il[(mmB * 3 + 2) * 2 + 0] + dl[(mmB * 3 + 2) * 2 + 1];
        float sc = xA + xB;
        #pragma unroll
        for (int off = 1; off < 64; off <<= 1) {
            float v = __shfl_up(sc, off);
            if (t >= off) sc += v;
        }
        Smid[mmB] = sc;
        Smid[mmA] = sc - xB;
        if (t == 0) Smid[0] = 0.f;
    }
    __syncthreads();
    float* uu  = coef + C_UU;
    float* dxM = coef + C_DXM;
    float* dxI = coef + C_DXI;
    float* wM  = coef + C_WM;
    float* wI  = coef + C_WI;
    float* dmd = coef + C_DMID;
    float* pi0 = coef + C_PI0;
    // one thread per source row k (online logsumexp, ~128 iters worst case)
    if (t < KK) {
        int k = t;
        if (k == 128) { uu[k] = 0.f; dxM[k] = 0.f; dxI[k] = 0.f; }
        else {
            int g  = (k < MP1) ? 0 : 1;
            int n0 = g ? (k - MP1) : (k + 1);
            float i0 = il[(n0 * 3 + g) * 2 + 0], i1 = il[(n0 * 3 + g) * 2 + 1];
            float e0 = dl[(n0 * 3 + g) * 2 + 0], e1 = dl[(n0 * 3 + g) * 2 + 1];
            float diagM = i0 + e0;
            float diagI = i1;
            float src   = i0 + e1;
            float mx = diagM, s = 1.f;
            { float e = diagI; if (e > mx) { s = s * expf(mx - e) + 1.f; mx = e; } else s += expf(e - mx); }
            for (int mp = n0 + 1; mp <= 128; ++mp) {
                float base = src + Smid[mp - 1] - Smid[n0];
                float eM = base + il[(mp * 3 + 2) * 2 + 0] + dl[(mp * 3 + 2) * 2 + 0];
                float eI = base + il[(mp * 3 + 2) * 2 + 1];
                if (eM > mx) { s = s * expf(mx - eM) + 1.f; mx = eM; } else s += expf(eM - mx);
                if (eI > mx) { s = s * expf(mx - eI) + 1.f; mx = eI; } else s += expf(eI - mx);
            }
            float lse = mx + logf(s);
            uu[k]  = expf(src - lse);
            dxM[k] = expf(diagM - lse);
            dxI[k] = expf(diagI - lse);
        }
    }
    for (int mp = t; mp < MP1; mp += 320) {
        wM[mp] = expf(il[(mp * 3 + 2) * 2 + 0] + dl[(mp * 3 + 2) * 2 + 0]);
        wI[mp] = expf(il[(mp * 3 + 2) * 2 + 1]);
    }
    for (int tt = t; tt < 128; tt += 320)
        dmd[tt] = (tt == 0) ? 1.f : expf(il[(tt * 3 + 2) * 2 + 0] + dl[(tt * 3 + 2) * 2 + 1]);
    __syncthreads();
    // pi0: wave 0, registers + shfl reductions (was the 110us scratch loop)
    if (t < 64) {
        float i00 = il[0], i01 = il[1], d00 = dl[0], d01 = dl[1];
        float va[5];
        float mx = -INFINITY;
        #pragma unroll
        for (int j = 0; j < 5; ++j) {
            int kp = t + 64 * j;
            float v = -INFINITY;
            if (kp < KK) {
                int mp = (kp < MP1) ? kp : (kp - MP1);
                int gp = (kp < MP1) ? 0 : 1;
                if (mp == 0) v = gp ? i01 : (i00 + d00);
                else {
                    float base = i00 + d01 + Smid[mp - 1];
                    v = base + (gp ? il[(mp * 3 + 2) * 2 + 1]
                                   : il[(mp * 3 + 2) * 2 + 0] + dl[(mp * 3 + 2) * 2 + 0]);
                }
            }
            va[j] = v;
            mx = fmaxf(mx, v);
        }
        #pragma unroll
        for (int off = 1; off < 64; off <<= 1) mx = fmaxf(mx, __shfl_xor(mx, off));
        float ssum = 0.f;
        #pragma unroll
        for (int j = 0; j < 5; ++j) {
            int kp = t + 64 * j;
            if (kp < KK) ssum += expf(va[j] - mx);
        }
        #pragma unroll
        for (int off = 1; off < 64; off <<= 1) ssum += __shfl_xor(ssum, off);
        float lse = mx + logf(ssum);
        #pragma unroll
        for (int j = 0; j < 5; ++j) {
            int kp = t + 64 * j;
            if (kp < KK) pi0[kp] = expf(va[j] - lse);
        }
    }
}

// -------- forward scan: one wave per batch, DPP affine scan, O(K) per step --------
__global__ __launch_bounds__(64) void k_fwd(const float* __restrict__ Eg,
                                            const int* __restrict__ tokg,
                                            const float* __restrict__ coef,
                                            float* __restrict__ out) {
    const float* uu  = coef + C_UU;
    const float* dxM = coef + C_DXM;
    const float* dxI = coef + C_DXI;
    const float* wMg = coef + C_WM;
    const float* wIg = coef + C_WI;
    const float* dmd = coef + C_DMID;
    const float* pi0 = coef + C_PI0;
    __shared__ float E[ETOK * EROW];
    __shared__ int tok[LL];
    int lane = threadIdx.x;
    int b = blockIdx.x;
    const float4* s4 = (const float4*)(Eg + (size_t)b * ETOK * EROW);
    float4* d4 = (float4*)E;
    for (int i = lane; i < ETOK * EROW / 4; i += 64) d4[i] = s4[i];
    ((int4*)tok)[lane] = ((const int4*)(tokg + b * LL))[lane];
    __syncthreads();

    int m0 = 2 * lane, m1 = 2 * lane + 1;
    bool L0 = (lane == 0), L63 = (lane == 63);
    float f63 = L63 ? 1.f : 0.f;
    float cM0 = L0 ? 0.f : uu[m0 - 1];
    float cI0 = uu[129 + m0];
    float cM1 = uu[m0];
    float cI1 = uu[129 + m1];
    float d0 = dmd[m0], d1v = dmd[m1];
    float Apair = d0 * d1v;
    float wM0 = wMg[m0], wM1 = wMg[m1], wI0 = wIg[m0], wI1 = wIg[m1];
    float xMA0 = L0 ? 0.f : dxM[m0 - 1], xIA0 = L0 ? 0.f : dxI[m0 - 1];
    float xMB0 = dxM[129 + m0], xIB0 = dxI[129 + m0];
    float xMA1 = dxM[m0], xIA1 = dxI[m0];
    float xMB1 = dxM[129 + m1], xIB1 = dxI[129 + m1];
    float wM2 = L63 ? wMg[128] : 0.f, wI2 = L63 ? wIg[128] : 0.f;
    float xMA2 = L63 ? dxM[127] : 0.f, xIA2 = L63 ? dxI[127] : 0.f;
    float xMB2 = L63 ? dxM[257] : 0.f, xIB2 = L63 ? dxI[257] : 0.f;

    // Kogge-Stone A-levels are step-invariant: precompute the per-level
    // accumulated multipliers (the scan's A-side never changes).
    float A0 = Apair;
    float A1 = A0 * updpp<0x111, 0xf, 0xf>(1.f, A0);
    float A2 = A1 * updpp<0x112, 0xf, 0xf>(1.f, A1);
    float A3 = A2 * updpp<0x114, 0xf, 0xf>(1.f, A2);
    float A4 = A3 * updpp<0x118, 0xf, 0xf>(1.f, A3);
    float A5 = A4 * updpp<0x142, 0xa, 0xf>(1.f, A4);

    int tk = tok[0];
    const float* Er = E + tk * EROW;
    float aM0 = pi0[m0] * Er[m0];
    float aM1 = pi0[m1] * Er[m1];
    float aI0 = pi0[129 + m0] * Er[130 + m0];
    float aI1 = pi0[129 + m1] * Er[130 + m1];
    float aM2 = f63 * pi0[128] * Er[128];
    float aI2 = f63 * pi0[257] * Er[258];

    float logZ = 0.f;
    float part = aM0 + aM1 + aI0 + aI1 + aM2 + aI2;

    // prefetch E row for step 1
    int tkc = tok[1];
    const float* Ep = E + tkc * EROW;
    float eM0 = Ep[m0], eM1 = Ep[m1];
    float eI0 = Ep[130 + m0], eI1 = Ep[130 + m1];
    float eM2 = Ep[128], eI2 = Ep[258];

    for (int l = 1; l < LL; ++l) {
        int tkn = tok[(l + 1 < LL) ? (l + 1) : 0];   // next-step token (prefetch)
        // rescale with previous step's sum (DPP reduce, runs parallel to scan)
        float s = wave_sum_to63(part);
        float stot = readlane_f(s, 63);
        float invs = 1.0f / stot;
        logZ += logf(stot);
        // neighbor alpha + forbidden-row broadcast (row 128 weight = 1.0/dest)
        float aMp  = updpp<0x138, 0xf, 0xf>(0.f, aM1);   // wf_shr:1
        float u128 = readlane_f(aM2, 63);
        float r0 = fmaf(aMp, cM0, aI0 * cI0);
        float r1 = fmaf(aM0, cM1, aI1 * cI1);
        // inclusive affine scan over 64 lanes: B-side only (A-side precomputed)
        float B = fmaf(d1v, r0, r1);
        B = fmaf(A0, updpp<0x111, 0xf, 0xf>(0.f, B), B);
        B = fmaf(A1, updpp<0x112, 0xf, 0xf>(0.f, B), B);
        B = fmaf(A2, updpp<0x114, 0xf, 0xf>(0.f, B), B);
        B = fmaf(A3, updpp<0x118, 0xf, 0xf>(0.f, B), B);
        B = fmaf(A4, updpp<0x142, 0xa, 0xf>(0.f, B), B);
        B = fmaf(A5, updpp<0x143, 0xc, 0xf>(0.f, B), B);
        float G0 = updpp<0x138, 0xf, 0xf>(0.f, B);       // exclusive: G[m0-1]
        float G1 = fmaf(d0, G0, r0);                      // G[m0]
        float G2 = B;                                     // lane63: G[127]
        float mM0 = wM0 * G0 + xMA0 * aMp + xMB0 * aI0 + u128;
        float mI0 = wI0 * G0 + xIA0 * aMp + xIB0 * aI0 + u128;
        float mM1 = wM1 * G1 + xMA1 * aM0 + xMB1 * aI1 + u128;
        float mI1 = wI1 * G1 + xIA1 * aM0 + xIB1 * aI1 + u128;
        float mM2 = wM2 * G2 + xMA2 * aM1 + xMB2 * aI2 + u128;
        float mI2 = wI2 * G2 + xIA2 * aM1 + xIB2 * aI2 + u128;
        aM0 = mM0 * (eM0 * invs);
        aM1 = mM1 * (eM1 * invs);
        aI0 = mI0 * (eI0 * invs);
        aI1 = mI1 * (eI1 * invs);
        aM2 = mM2 * (eM2 * invs) * f63;
        aI2 = mI2 * (eI2 * invs) * f63;
        part = ((aM0 + aM1) + (aI0 + aI1)) + (aM2 + aI2);
        // prefetch next step's E row (latency spans the next scan)
        const float* En = E + tkn * EROW;
        eM0 = En[m0]; eM1 = En[m1];
        eI0 = En[130 + m0]; eI1 = En[130 + m1];
        eM2 = En[128]; eI2 = En[258];
    }
    float s = wave_sum_to63(part);
    if (lane == 63) out[b] = logZ + logf(s);
}

extern "C" void kernel_launch(void* const* d_in, const int* in_sizes, int n_in,
                              void* d_out, int out_size, void* d_ws, size_t ws_size,
                              hipStream_t stream) {
    const float* data  = (const float*)d_in[0];
    const float* z     = (const float*)d_in[1];
    const float* dec_W = (const float*)d_in[2];
    const float* dec_b = (const float*)d_in[3];
    const float* ins   = (const float*)d_in[4];
    const float* del   = (const float*)d_in[5];
    const float* invt  = (const float*)d_in[6];
    float* out = (float*)d_out;

    float* ws   = (float*)d_ws;
    float* E    = ws;
    int*   tok  = (int*)(ws + OFF_TOK);
    float* coef = ws + OFF_COEF;

    k_emis<<<BB * 2 * MP1 / 2, 64, 0, stream>>>(z, dec_W, dec_b, invt, E);
    k_tok<<<(BB * LL + 255) / 256, 256, 0, stream>>>(data, tok);
    k_trans<<<1, 320, 0, stream>>>(ins, del, coef);
    k_fwd<<<BB, 64, 0, stream>>>(E, tok, coef, out);
}

// Round 5
// 91.741 us; speedup vs baseline: 2.1850x; 1.3370x over previous
//
#include <hip/hip_runtime.h>
#include <math.h>

// FactorMuE: profile-HMM forward log-likelihood.
// Dims (static): M=128, Mp1=129, K=258, D=21, ZD=64, B=64, L=256, P=774.
// Reference-fidelity detail: row k=128 of the transition matrix is all
// NEG=-1e32; the reference's float32 row-lse absorbs log(258), so the
// normalized row is 0.0 -> linear outflow weight 1.0 PER DESTINATION.
#define MP1 129
#define KK  258
#define DD  21
#define ZDIM 64
#define BB  64
#define LL  256
#define EROW 260   // E row: match m at col m (0..128), 129 unused, insert m at 130+m, pad 259
#define ETOK 22    // 21 tokens + ones row (index 21 = missing)

// ---------------- ws layout (floats) ----------------
#define OFF_TOK  366080
#define OFF_COEF 382464
#define C_UU   0
#define C_DXM  258
#define C_DXI  516
#define C_WM   774
#define C_WI   903
#define C_DMID 1032
#define C_PI0  1160

#define EMIS_BLKS 2064   // 16512 rows / 8 per block
#define TOK_BLKS  64     // 16384 items / 256

// -------- DPP helpers (cross-lane on the VALU pipe) --------
template <int CTRL, int RM, int BM>
__device__ __forceinline__ float updpp(float old, float src) {
    return __int_as_float(__builtin_amdgcn_update_dpp(
        __float_as_int(old), __float_as_int(src), CTRL, RM, BM, false));
}
__device__ __forceinline__ float readlane_f(float v, int lane) {
    return __int_as_float(__builtin_amdgcn_readlane(__float_as_int(v), lane));
}
__device__ __forceinline__ float wave_sum_to63(float s) {
    s += updpp<0x111, 0xf, 0xf>(0.f, s);   // row_shr:1
    s += updpp<0x112, 0xf, 0xf>(0.f, s);   // row_shr:2
    s += updpp<0x114, 0xf, 0xf>(0.f, s);   // row_shr:4
    s += updpp<0x118, 0xf, 0xf>(0.f, s);   // row_shr:8
    s += updpp<0x142, 0xa, 0xf>(0.f, s);   // row_bcast:15
    s += updpp<0x143, 0xc, 0xf>(0.f, s);   // row_bcast:31
    return s;
}

// ==================== fused setup: emis | tok | trans by block role ====================
__global__ __launch_bounds__(256) void k_setup(const float* __restrict__ z,
                                               const float* __restrict__ W,
                                               const float* __restrict__ bias,
                                               const float* __restrict__ invt,
                                               const float* __restrict__ data,
                                               const float* __restrict__ ins,
                                               const float* __restrict__ del,
                                               float* __restrict__ E,
                                               int* __restrict__ tokout,
                                               float* __restrict__ coef) {
    __shared__ float il[774], dl[774], Smid[129];
    int bid = blockIdx.x;
    int tid = threadIdx.x;

    if (bid < EMIS_BLKS) {
        // ---- emission: 8 rows of 32 lanes per block ----
        int half = tid >> 5;
        int d    = tid & 31;
        int row  = bid * 8 + half;                 // [0, 16512)
        int b    = row / (2 * MP1);
        int rem  = row % (2 * MP1);
        int c    = rem / MP1;
        int m    = rem % MP1;
        float it = log1pf(expf(invt[0]));          // softplus
        float v  = -INFINITY;
        if (d < DD) {
            int od = (c * MP1 + m) * DD + d;
            const float4* zr = (const float4*)(z + (size_t)b * ZDIM);
            const float4* wr = (const float4*)(W + (size_t)od * ZDIM);
            float acc = bias[od];
            #pragma unroll
            for (int j = 0; j < ZDIM / 4; ++j) {
                float4 a = zr[j], w = wr[j];
                acc += a.x * w.x + a.y * w.y + a.z * w.z + a.w * w.w;
            }
            v = acc * it;
        }
        float mx = v;
        #pragma unroll
        for (int off = 16; off >= 1; off >>= 1) mx = fmaxf(mx, __shfl_xor(mx, off, 32));
        float p = (d < DD) ? expf(v - mx) : 0.f;
        float s = p;
        #pragma unroll
        for (int off = 16; off >= 1; off >>= 1) s += __shfl_xor(s, off, 32);
        int col = (c == 0) ? m : (130 + m);
        float* Eb = E + (size_t)b * ETOK * EROW;
        if (d < DD)  Eb[d * EROW + col] = p / s;
        if (d == DD) Eb[DD * EROW + col] = 1.0f;
        return;
    }
    if (bid < EMIS_BLKS + TOK_BLKS) {
        // ---- token extraction ----
        int i = (bid - EMIS_BLKS) * 256 + tid;     // < 16384
        const float* r = data + (size_t)i * DD;
        int idx = DD; float ssum = 0.f;
        for (int d = 0; d < DD; ++d) { float vv = r[d]; ssum += vv; if (vv > 0.5f) idx = d; }
        tokout[i] = (ssum > 0.5f) ? idx : DD;
        return;
    }
    // ---- transition coefficients (single block) ----
    int t = tid;
    for (int p = t; p < 387; p += 256) {
        float x0 = ins[2 * p], x1 = ins[2 * p + 1];
        float mx = fmaxf(x0, x1);
        float ls = mx + logf(expf(x0 - mx) + expf(x1 - mx));
        il[2 * p] = x0 - ls; il[2 * p + 1] = x1 - ls;
        float y0 = del[2 * p], y1 = del[2 * p + 1];
        float my = fmaxf(y0, y1);
        float lt = my + logf(expf(y0 - my) + expf(y1 - my));
        dl[2 * p] = y0 - lt; dl[2 * p + 1] = y1 - lt;
    }
    __syncthreads();
    if (t < 64) {   // Smid prefix sum, wave 0
        int mmA = 1 + 2 * t, mmB = 2 + 2 * t;
        float xA = il[(mmA * 3 + 2) * 2 + 0] + dl[(mmA * 3 + 2) * 2 + 1];
        float xB = il[(mmB * 3 + 2) * 2 + 0] + dl[(mmB * 3 + 2) * 2 + 1];
        float sc = xA + xB;
        #pragma unroll
        for (int off = 1; off < 64; off <<= 1) {
            float vv = __shfl_up(sc, off);
            if (t >= off) sc += vv;
        }
        Smid[mmB] = sc;
        Smid[mmA] = sc - xB;
        if (t == 0) Smid[0] = 0.f;
    }
    __syncthreads();
    float* uu  = coef + C_UU;
    float* dxM = coef + C_DXM;
    float* dxI = coef + C_DXI;
    float* wM  = coef + C_WM;
    float* wI  = coef + C_WI;
    float* dmd = coef + C_DMID;
    float* pi0 = coef + C_PI0;
    for (int k = t; k < KK; k += 256) {
        if (k == 128) { uu[k] = 0.f; dxM[k] = 0.f; dxI[k] = 0.f; continue; }
        int g  = (k < MP1) ? 0 : 1;
        int n0 = g ? (k - MP1) : (k + 1);
        float i0 = il[(n0 * 3 + g) * 2 + 0], i1 = il[(n0 * 3 + g) * 2 + 1];
        float e0 = dl[(n0 * 3 + g) * 2 + 0], e1 = dl[(n0 * 3 + g) * 2 + 1];
        float diagM = i0 + e0;
        float diagI = i1;
        float src   = i0 + e1;
        float mx = diagM, s = 1.f;
        { float e = diagI; if (e > mx) { s = s * expf(mx - e) + 1.f; mx = e; } else s += expf(e - mx); }
        for (int mp = n0 + 1; mp <= 128; ++mp) {
            float base = src + Smid[mp - 1] - Smid[n0];
            float eM = base + il[(mp * 3 + 2) * 2 + 0] + dl[(mp * 3 + 2) * 2 + 0];
            float eI = base + il[(mp * 3 + 2) * 2 + 1];
            if (eM > mx) { s = s * expf(mx - eM) + 1.f; mx = eM; } else s += expf(eM - mx);
            if (eI > mx) { s = s * expf(mx - eI) + 1.f; mx = eI; } else s += expf(eI - mx);
        }
        float lse = mx + logf(s);
        uu[k]  = expf(src - lse);
        dxM[k] = expf(diagM - lse);
        dxI[k] = expf(diagI - lse);
    }
    for (int mp = t; mp < MP1; mp += 256) {
        wM[mp] = expf(il[(mp * 3 + 2) * 2 + 0] + dl[(mp * 3 + 2) * 2 + 0]);
        wI[mp] = expf(il[(mp * 3 + 2) * 2 + 1]);
    }
    for (int tt = t; tt < 128; tt += 256)
        dmd[tt] = (tt == 0) ? 1.f : expf(il[(tt * 3 + 2) * 2 + 0] + dl[(tt * 3 + 2) * 2 + 1]);
    __syncthreads();
    if (t < 64) {   // pi0 in registers, wave 0
        float i00 = il[0], i01 = il[1], d00 = dl[0], d01 = dl[1];
        float va[5];
        float mx = -INFINITY;
        #pragma unroll
        for (int j = 0; j < 5; ++j) {
            int kp = t + 64 * j;
            float v = -INFINITY;
            if (kp < KK) {
                int mp = (kp < MP1) ? kp : (kp - MP1);
                int gp = (kp < MP1) ? 0 : 1;
                if (mp == 0) v = gp ? i01 : (i00 + d00);
                else {
                    float base = i00 + d01 + Smid[mp - 1];
                    v = base + (gp ? il[(mp * 3 + 2) * 2 + 1]
                                   : il[(mp * 3 + 2) * 2 + 0] + dl[(mp * 3 + 2) * 2 + 0]);
                }
            }
            va[j] = v;
            mx = fmaxf(mx, v);
        }
        #pragma unroll
        for (int off = 1; off < 64; off <<= 1) mx = fmaxf(mx, __shfl_xor(mx, off));
        float ssum = 0.f;
        #pragma unroll
        for (int j = 0; j < 5; ++j) {
            int kp = t + 64 * j;
            if (kp < KK) ssum += expf(va[j] - mx);
        }
        #pragma unroll
        for (int off = 1; off < 64; off <<= 1) ssum += __shfl_xor(ssum, off);
        float lse = mx + logf(ssum);
        #pragma unroll
        for (int j = 0; j < 5; ++j) {
            int kp = t + 64 * j;
            if (kp < KK) pi0[kp] = expf(va[j] - lse);
        }
    }
}

// ==================== forward scan ====================
// Exponent-only rescale: invs = 2^-e (exact), e accumulated as integer;
// rescale every 2nd step (drift bounded ~2^17, fp32-safe). No div/log in loop.
__global__ __launch_bounds__(64) void k_fwd(const float* __restrict__ Eg,
                                            const int* __restrict__ tokg,
                                            const float* __restrict__ coef,
                                            float* __restrict__ out) {
    const float* uu  = coef + C_UU;
    const float* dxM = coef + C_DXM;
    const float* dxI = coef + C_DXI;
    const float* wMg = coef + C_WM;
    const float* wIg = coef + C_WI;
    const float* dmd = coef + C_DMID;
    const float* pi0 = coef + C_PI0;
    __shared__ float E[ETOK * EROW];
    __shared__ int tok[LL];
    int lane = threadIdx.x;
    int b = blockIdx.x;
    const float4* s4 = (const float4*)(Eg + (size_t)b * ETOK * EROW);
    float4* d4 = (float4*)E;
    for (int i = lane; i < ETOK * EROW / 4; i += 64) d4[i] = s4[i];
    ((int4*)tok)[lane] = ((const int4*)(tokg + b * LL))[lane];
    __syncthreads();

    int m0 = 2 * lane, m1 = 2 * lane + 1;
    bool L0 = (lane == 0), L63 = (lane == 63);
    float f63 = L63 ? 1.f : 0.f;
    float cM0 = L0 ? 0.f : uu[m0 - 1];
    float cI0 = uu[129 + m0];
    float cM1 = uu[m0];
    float cI1 = uu[129 + m1];
    float d0 = dmd[m0], d1v = dmd[m1];
    float Apair = d0 * d1v;
    float wM0 = wMg[m0], wM1 = wMg[m1], wI0 = wIg[m0], wI1 = wIg[m1];
    float xMA0 = L0 ? 0.f : dxM[m0 - 1], xIA0 = L0 ? 0.f : dxI[m0 - 1];
    float xMB0 = dxM[129 + m0], xIB0 = dxI[129 + m0];
    float xMA1 = dxM[m0], xIA1 = dxI[m0];
    float xMB1 = dxM[129 + m1], xIB1 = dxI[129 + m1];
    float wM2 = L63 ? wMg[128] : 0.f, wI2 = L63 ? wIg[128] : 0.f;
    float xMA2 = L63 ? dxM[127] : 0.f, xIA2 = L63 ? dxI[127] : 0.f;
    float xMB2 = L63 ? dxM[257] : 0.f, xIB2 = L63 ? dxI[257] : 0.f;

    // step-invariant Kogge-Stone A-levels
    float A0 = Apair;
    float A1 = A0 * updpp<0x111, 0xf, 0xf>(1.f, A0);
    float A2 = A1 * updpp<0x112, 0xf, 0xf>(1.f, A1);
    float A3 = A2 * updpp<0x114, 0xf, 0xf>(1.f, A2);
    float A4 = A3 * updpp<0x118, 0xf, 0xf>(1.f, A3);
    float A5 = A4 * updpp<0x142, 0xa, 0xf>(1.f, A4);

    int tk = tok[0];
    const float* Er0 = E + tk * EROW;
    float aM0 = pi0[m0] * Er0[m0];
    float aM1 = pi0[m1] * Er0[m1];
    float aI0 = pi0[129 + m0] * Er0[130 + m0];
    float aI1 = pi0[129 + m1] * Er0[130 + m1];
    float aM2 = f63 * pi0[128] * Er0[128];
    float aI2 = f63 * pi0[257] * Er0[258];

    int etot = 0;
    float part = aM0 + aM1 + aI0 + aI1 + aM2 + aI2;

    // E-row ping-pong buffers: X = odd steps, Y = even steps
    float xm0, xm1, xi0, xi1, xm2g, xi2g;
    float ym0, ym1, yi0, yi1, ym2g, yi2g;
    { const float* Er = E + tok[1] * EROW;
      xm0 = Er[m0]; xm1 = Er[m1]; xi0 = Er[130 + m0]; xi1 = Er[130 + m1];
      xm2g = Er[128]; xi2g = Er[258]; }
    { const float* Er = E + tok[2] * EROW;
      ym0 = Er[m0]; ym1 = Er[m1]; yi0 = Er[130 + m0]; yi1 = Er[130 + m1];
      ym2g = Er[128]; yi2g = Er[258]; }
    int t2 = tok[3];   // token for step l+2 (refills X)
    int t3 = tok[4];   // token for step l+3 (refills Y)

#define STEP_BODY(DO_RESCALE, EM0_, EM1_, EI0_, EI1_, EM2_, EI2_)            \
    {                                                                        \
        float invs = 1.0f;                                                   \
        if (DO_RESCALE) {                                                    \
            float s_ = wave_sum_to63(part);                                  \
            float stot = readlane_f(s_, 63);                                 \
            int sb = __float_as_int(stot) & 0x7f800000;                      \
            etot += (sb >> 23);                                              \
            invs = __int_as_float(0x7f000000 - sb);                          \
        }                                                                    \
        float aMp  = updpp<0x138, 0xf, 0xf>(0.f, aM1);  /* wf_shr:1 */       \
        float u128 = readlane_f(aM2, 63);                                    \
        float r0 = fmaf(aMp, cM0, aI0 * cI0);                                \
        float r1 = fmaf(aM0, cM1, aI1 * cI1);                                \
        float B = fmaf(d1v, r0, r1);                                         \
        B = fmaf(A0, updpp<0x111, 0xf, 0xf>(0.f, B), B);                     \
        B = fmaf(A1, updpp<0x112, 0xf, 0xf>(0.f, B), B);                     \
        B = fmaf(A2, updpp<0x114, 0xf, 0xf>(0.f, B), B);                     \
        B = fmaf(A3, updpp<0x118, 0xf, 0xf>(0.f, B), B);                     \
        B = fmaf(A4, updpp<0x142, 0xa, 0xf>(0.f, B), B);                     \
        B = fmaf(A5, updpp<0x143, 0xc, 0xf>(0.f, B), B);                     \
        float G0 = updpp<0x138, 0xf, 0xf>(0.f, B);                           \
        float G1 = fmaf(d0, G0, r0);                                         \
        float G2 = B;                                                        \
        float mM0 = fmaf(wM0, G0, fmaf(xMA0, aMp, fmaf(xMB0, aI0, u128)));   \
        float mI0 = fmaf(wI0, G0, fmaf(xIA0, aMp, fmaf(xIB0, aI0, u128)));   \
        float mM1 = fmaf(wM1, G1, fmaf(xMA1, aM0, fmaf(xMB1, aI1, u128)));   \
        float mI1 = fmaf(wI1, G1, fmaf(xIA1, aM0, fmaf(xIB1, aI1, u128)));   \
        float mM2 = fmaf(wM2, G2, fmaf(xMA2, aM1, fmaf(xMB2, aI2, u128)));   \
        float mI2 = fmaf(wI2, G2, fmaf(xIA2, aM1, fmaf(xIB2, aI2, u128)));   \
        aM0 = mM0 * (EM0_ * invs);                                           \
        aM1 = mM1 * (EM1_ * invs);                                           \
        aI0 = mI0 * (EI0_ * invs);                                           \
        aI1 = mI1 * (EI1_ * invs);                                           \
        aM2 = mM2 * (EM2_ * invs) * f63;                                     \
        aI2 = mI2 * (EI2_ * invs) * f63;                                     \
        part = ((aM0 + aM1) + (aI0 + aI1)) + (aM2 + aI2);                    \
    }

    // 127 pairs: steps l = 2*it+1 (X, rescale) and l+1 (Y, no rescale)
    for (int it = 0; it < 127; ++it) {
        int l = 1 + 2 * it;
        STEP_BODY(1, xm0, xm1, xi0, xi1, xm2g, xi2g);
        { const float* Er = E + t2 * EROW;            // refill X for step l+2
          xm0 = Er[m0]; xm1 = Er[m1]; xi0 = Er[130 + m0]; xi1 = Er[130 + m1];
          xm2g = Er[128]; xi2g = Er[258]; }
        int nt2 = tok[(l + 4) & 255];
        STEP_BODY(0, ym0, ym1, yi0, yi1, ym2g, yi2g);
        { const float* Er = E + t3 * EROW;            // refill Y for step l+3
          ym0 = Er[m0]; ym1 = Er[m1]; yi0 = Er[130 + m0]; yi1 = Er[130 + m1];
          ym2g = Er[128]; yi2g = Er[258]; }
        int nt3 = tok[(l + 5) & 255];
        t2 = nt2; t3 = nt3;
    }
    // final step l = 255 (X buffer, rescale)
    STEP_BODY(1, xm0, xm1, xi0, xi1, xm2g, xi2g);
#undef STEP_BODY

    float s = wave_sum_to63(part);
    if (lane == 63)
        out[b] = (float)(etot - 127 * 128) * 0.6931471805599453f + logf(s);
}

extern "C" void kernel_launch(void* const* d_in, const int* in_sizes, int n_in,
                              void* d_out, int out_size, void* d_ws, size_t ws_size,
                              hipStream_t stream) {
    const float* data  = (const float*)d_in[0];
    const float* z     = (const float*)d_in[1];
    const float* dec_W = (const float*)d_in[2];
    const float* dec_b = (const float*)d_in[3];
    const float* ins   = (const float*)d_in[4];
    const float* del   = (const float*)d_in[5];
    const float* invt  = (const float*)d_in[6];
    float* out = (float*)d_out;

    float* ws   = (float*)d_ws;
    float* E    = ws;
    int*   tok  = (int*)(ws + OFF_TOK);
    float* coef = ws + OFF_COEF;

    k_setup<<<EMIS_BLKS + TOK_BLKS + 1, 256, 0, stream>>>(z, dec_W, dec_b, invt,
                                                          data, ins, del, E, tok, coef);
    k_fwd<<<BB, 64, 0, stream>>>(E, tok, coef, out);
}

// Round 6
// 62.069 us; speedup vs baseline: 3.2296x; 1.4781x over previous
//
#include <hip/hip_runtime.h>
#include <math.h>

// FactorMuE: profile-HMM forward log-likelihood.
// Dims (static): M=128, Mp1=129, K=258, D=21, ZD=64, B=64, L=256, P=774.
// Reference-fidelity detail: row k=128 of the transition matrix is all
// NEG=-1e32; the reference's float32 row-lse absorbs log(258), so the
// normalized row is 0.0 -> linear outflow weight 1.0 PER DESTINATION.
#define MP1 129
#define KK  258
#define DD  21
#define ZDIM 64
#define BB  64
#define LL  256
// E row layout: match m at col m (0..128), col 129 pad, insert m at col 130+m
// (130..258), col 259 pad, col 260 = dup of match-128, col 261 = dup of
// insert-128 (so the lane-63 pair is one aligned b64 read), cols 262-263 pad.
#define EROW 264
#define ETOK 22    // 21 tokens + ones row (index 21 = missing)

// ---------------- ws layout (floats) ----------------
#define OFF_TOK  371712            // 64*22*264
#define OFF_COEF 388096
#define C_UU   0
#define C_DXM  258
#define C_DXI  516
#define C_WM   774
#define C_WI   903
#define C_DMID 1032
#define C_PI0  1160

#define EMIS_BLKS 65   // 65*4 = 260 >= 258 (c,m)-rows, one wave per row
#define TOK_BLKS  32   // 128 waves, 3 rows/wave/iter, 43 iters

typedef float f32x2 __attribute__((ext_vector_type(2)));

// -------- DPP helpers (cross-lane on the VALU pipe) --------
template <int CTRL, int RM, int BM>
__device__ __forceinline__ float updpp(float old, float src) {
    return __int_as_float(__builtin_amdgcn_update_dpp(
        __float_as_int(old), __float_as_int(src), CTRL, RM, BM, false));
}
__device__ __forceinline__ float readlane_f(float v, int lane) {
    return __int_as_float(__builtin_amdgcn_readlane(__float_as_int(v), lane));
}
__device__ __forceinline__ float wave_sum_to63(float s) {
    s += updpp<0x111, 0xf, 0xf>(0.f, s);   // row_shr:1
    s += updpp<0x112, 0xf, 0xf>(0.f, s);   // row_shr:2
    s += updpp<0x114, 0xf, 0xf>(0.f, s);   // row_shr:4
    s += updpp<0x118, 0xf, 0xf>(0.f, s);   // row_shr:8
    s += updpp<0x142, 0xa, 0xf>(0.f, s);   // row_bcast:15
    s += updpp<0x143, 0xc, 0xf>(0.f, s);   // row_bcast:31
    return s;
}

// ==================== fused setup: emis | tok | coef by block role ====================
__global__ __launch_bounds__(256) void k_setup(const float* __restrict__ z,
                                               const float* __restrict__ W,
                                               const float* __restrict__ bias,
                                               const float* __restrict__ invt,
                                               const float* __restrict__ data,
                                               const float* __restrict__ ins,
                                               const float* __restrict__ del,
                                               float* __restrict__ E,
                                               int* __restrict__ tokout,
                                               float* __restrict__ coef) {
    __shared__ float il[774], dl[774], Smid[129], Qs[130];
    int bid = blockIdx.x;
    int tid = threadIdx.x;

    if (bid < EMIS_BLKS) {
        // ---- emission: wave = one (c,m)-row rr, lane = batch b ----
        int b  = tid & 63;
        int rr = __builtin_amdgcn_readfirstlane(bid * 4 + (tid >> 6));
        if (rr >= KK) return;
        float it = log1pf(expf(invt[0]));          // softplus
        float4 zr[16];                             // z[b] row in VGPRs
        const float4* zp = (const float4*)(z + (size_t)b * ZDIM);
        #pragma unroll
        for (int j = 0; j < 16; ++j) zr[j] = zp[j];
        const float* wb = W + (size_t)rr * DD * ZDIM;   // wave-uniform
        const float* bp = bias + rr * DD;
        float acc[DD];
        #pragma unroll
        for (int d = 0; d < DD; ++d) {
            const float4* wp = (const float4*)(wb + d * ZDIM);
            float a = bp[d];
            #pragma unroll
            for (int j = 0; j < 16; ++j) {
                float4 w4 = wp[j];
                a += zr[j].x * w4.x + zr[j].y * w4.y + zr[j].z * w4.z + zr[j].w * w4.w;
            }
            acc[d] = a * it;
        }
        float mx = acc[0];
        #pragma unroll
        for (int d = 1; d < DD; ++d) mx = fmaxf(mx, acc[d]);
        float s = 0.f;
        #pragma unroll
        for (int d = 0; d < DD; ++d) { acc[d] = expf(acc[d] - mx); s += acc[d]; }
        float inv = 1.0f / s;
        float* Eb = E + (size_t)b * ETOK * EROW;
        int col = (rr < MP1) ? rr : (rr + 1);      // insert m -> 130+m
        int dup = (rr == 128) ? 260 : ((rr == 257) ? 261 : -1);
        #pragma unroll
        for (int d = 0; d < DD; ++d) {
            float v = acc[d] * inv;
            Eb[d * EROW + col] = v;
            if (dup >= 0) Eb[d * EROW + dup] = v;
        }
        Eb[DD * EROW + col] = 1.0f;                // ones row (missing token)
        if (dup >= 0) Eb[DD * EROW + dup] = 1.0f;
        return;
    }
    if (bid < EMIS_BLKS + TOK_BLKS) {
        // ---- token extraction via ballot: 3 rows per wave-iter ----
        int wid  = (bid - EMIS_BLKS) * 4 + (tid >> 6);   // 0..127
        int lane = tid & 63;
        int r3   = lane / 21;                            // 0..3 (lane 63 idle)
        int d    = lane - r3 * 21;
        for (int base = wid * 3; base < BB * LL; base += 128 * 3) {
            int row = base + r3;
            float v = 0.f;
            if (r3 < 3 && row < BB * LL) v = data[(size_t)row * DD + d];
            unsigned long long m = __ballot(v > 0.5f);
            if (r3 < 3 && d == 0 && row < BB * LL) {
                unsigned long long slice = (m >> (21 * r3)) & 0x1FFFFFULL;
                tokout[row] = slice ? (int)__builtin_ctzll(slice) : DD;
            }
        }
        return;
    }
    // ---- transition coefficients (single block, O(1) per row via suffix-LSE) ----
    int t = tid;
    for (int p = t; p < 387; p += 256) {
        float x0 = ins[2 * p], x1 = ins[2 * p + 1];
        float mx = fmaxf(x0, x1);
        float ls = mx + logf(expf(x0 - mx) + expf(x1 - mx));
        il[2 * p] = x0 - ls; il[2 * p + 1] = x1 - ls;
        float y0 = del[2 * p], y1 = del[2 * p + 1];
        float my = fmaxf(y0, y1);
        float lt = my + logf(expf(y0 - my) + expf(y1 - my));
        dl[2 * p] = y0 - lt; dl[2 * p + 1] = y1 - lt;
    }
    __syncthreads();
    if (t < 64) {   // Smid prefix sum, wave 0
        int mmA = 1 + 2 * t, mmB = 2 + 2 * t;
        float xA = il[(mmA * 3 + 2) * 2 + 0] + dl[(mmA * 3 + 2) * 2 + 1];
        float xB = il[(mmB * 3 + 2) * 2 + 0] + dl[(mmB * 3 + 2) * 2 + 1];
        float sc = xA + xB;
        #pragma unroll
        for (int off = 1; off < 64; off <<= 1) {
            float vv = __shfl_up(sc, off);
            if (t >= off) sc += vv;
        }
        Smid[mmB] = sc;
        Smid[mmA] = sc - xB;
        if (t == 0) Smid[0] = 0.f;
    }
    __syncthreads();
    if (t < 64) {
        // suffix-LSE over P[mp] = Smid[mp-1] + LSE(ilM+dlM, ilI), mp=1..128.
        // Reverse order: lane t holds R[2t]=P[128-2t], R[2t+1]=P[127-2t];
        // inclusive (m,s)-scan gives Q[j] = LSE_{mp>=j} P[mp].
        int mpA = 128 - 2 * t, mpB = 127 - 2 * t;
        float aM_ = il[(mpA * 3 + 2) * 2 + 0] + dl[(mpA * 3 + 2) * 2 + 0];
        float aI_ = il[(mpA * 3 + 2) * 2 + 1];
        float mA = fmaxf(aM_, aI_);
        float pA = Smid[mpA - 1] + mA + logf(expf(aM_ - mA) + expf(aI_ - mA));
        float bM_ = il[(mpB * 3 + 2) * 2 + 0] + dl[(mpB * 3 + 2) * 2 + 0];
        float bI_ = il[(mpB * 3 + 2) * 2 + 1];
        float mB = fmaxf(bM_, bI_);
        float pB = Smid[mpB - 1] + mB + logf(expf(bM_ - mB) + expf(bI_ - mB));
        float cm = fmaxf(pA, pB);
        float cs = expf(pA - cm) + expf(pB - cm);
        #pragma unroll
        for (int off = 1; off < 64; off <<= 1) {
            float om = __shfl_up(cm, off);
            float os = __shfl_up(cs, off);
            if (t >= off) {
                float M = fmaxf(cm, om);
                cs = cs * expf(cm - M) + os * expf(om - M);
                cm = M;
            }
        }
        Qs[mpB] = cm + logf(cs);                   // odd j (127-2t)
        float em = __shfl_up(cm, 1), es = __shfl_up(cs, 1);
        if (t == 0) Qs[128] = pA;
        else {
            float M = fmaxf(em, pA);
            Qs[mpA] = M + logf(es * expf(em - M) + expf(pA - M));
        }
        if (t == 0) Qs[129] = -1e30f;
    }
    __syncthreads();
    float* uu  = coef + C_UU;
    float* dxM = coef + C_DXM;
    float* dxI = coef + C_DXI;
    float* wM  = coef + C_WM;
    float* wI  = coef + C_WI;
    float* dmd = coef + C_DMID;
    float* pi0 = coef + C_PI0;
    for (int k = t; k < KK; k += 256) {
        if (k == 128) { uu[k] = 0.f; dxM[k] = 0.f; dxI[k] = 0.f; continue; }
        int g  = (k < MP1) ? 0 : 1;
        int n0 = g ? (k - MP1) : (k + 1);
        float i0 = il[(n0 * 3 + g) * 2 + 0], i1 = il[(n0 * 3 + g) * 2 + 1];
        float e0 = dl[(n0 * 3 + g) * 2 + 0], e1 = dl[(n0 * 3 + g) * 2 + 1];
        float diagM = i0 + e0;
        float diagI = i1;
        float src   = i0 + e1;
        float tail  = src - Smid[n0] + Qs[n0 + 1];
        float M3 = fmaxf(fmaxf(diagM, diagI), tail);
        float ssum = expf(diagM - M3) + expf(diagI - M3) + expf(tail - M3);
        float lse = M3 + logf(ssum);
        uu[k]  = expf(src - lse);
        dxM[k] = expf(diagM - lse);
        dxI[k] = expf(diagI - lse);
    }
    for (int mp = t; mp < MP1; mp += 256) {
        wM[mp] = expf(il[(mp * 3 + 2) * 2 + 0] + dl[(mp * 3 + 2) * 2 + 0]);
        wI[mp] = expf(il[(mp * 3 + 2) * 2 + 1]);
    }
    for (int tt = t; tt < 128; tt += 256)
        dmd[tt] = (tt == 0) ? 1.f : expf(il[(tt * 3 + 2) * 2 + 0] + dl[(tt * 3 + 2) * 2 + 1]);
    __syncthreads();
    {   // pi0: O(1) per state via Qs
        float i00 = il[0], i01 = il[1], d00 = dl[0], d01 = dl[1];
        float a00 = i00 + d00, a0129 = i01;
        float tail0 = i00 + d01 + Qs[1];
        float M3 = fmaxf(fmaxf(a00, a0129), tail0);
        float lse0 = M3 + logf(expf(a00 - M3) + expf(a0129 - M3) + expf(tail0 - M3));
        for (int kp = t; kp < KK; kp += 256) {
            int gp = (kp >= MP1);
            int mp = gp ? (kp - MP1) : kp;
            float v;
            if (mp == 0) v = gp ? a0129 : a00;
            else v = i00 + d01 + Smid[mp - 1] +
                     (gp ? il[(mp * 3 + 2) * 2 + 1]
                         : il[(mp * 3 + 2) * 2 + 0] + dl[(mp * 3 + 2) * 2 + 0]);
            pi0[kp] = expf(v - lse0);
        }
    }
}

// ==================== forward scan: 1 wave/batch, packed f32x2 updates ====================
__global__ __launch_bounds__(64) void k_fwd(const float* __restrict__ Eg,
                                            const int* __restrict__ tokg,
                                            const float* __restrict__ coef,
                                            float* __restrict__ out) {
    const float* uu  = coef + C_UU;
    const float* dxM = coef + C_DXM;
    const float* dxI = coef + C_DXI;
    const float* wMg = coef + C_WM;
    const float* wIg = coef + C_WI;
    const float* dmd = coef + C_DMID;
    const float* pi0 = coef + C_PI0;
    __shared__ float Es[ETOK * EROW];
    __shared__ int tokL[LL];
    int lane = threadIdx.x;
    int b = blockIdx.x;
    const float4* s4 = (const float4*)(Eg + (size_t)b * ETOK * EROW);
    float4* d4 = (float4*)Es;
    for (int i = lane; i < ETOK * EROW / 4; i += 64) d4[i] = s4[i];
    ((int4*)tokL)[lane] = ((const int4*)(tokg + b * LL))[lane];
    __syncthreads();

    int m0 = 2 * lane, m1 = 2 * lane + 1;
    bool L0 = (lane == 0), L63 = (lane == 63);
    float f63 = L63 ? 1.f : 0.f;
    float cM0 = L0 ? 0.f : uu[m0 - 1];
    float cI0 = uu[129 + m0];
    float cM1 = uu[m0];
    float cI1 = uu[129 + m1];
    float d0 = dmd[m0], d1v = dmd[m1];
    float Apair = d0 * d1v;
    // packed per-destination coefficients (0/1 = m0/m1 axis)
    f32x2 wMp  = {wMg[m0], wMg[m1]};
    f32x2 wIp  = {wIg[m0], wIg[m1]};
    f32x2 xMAp = {L0 ? 0.f : dxM[m0 - 1], dxM[m0]};
    f32x2 xIAp = {L0 ? 0.f : dxI[m0 - 1], dxI[m0]};
    f32x2 xMBp = {dxM[129 + m0], dxM[129 + m1]};
    f32x2 xIBp = {dxI[129 + m0], dxI[129 + m1]};
    // lane-63 (M2/I2 axis) pair
    f32x2 w2p  = {L63 ? wMg[128] : 0.f, L63 ? wIg[128] : 0.f};
    f32x2 xA2p = {L63 ? dxM[127] : 0.f, L63 ? dxI[127] : 0.f};
    f32x2 xB2p = {L63 ? dxM[257] : 0.f, L63 ? dxI[257] : 0.f};
    f32x2 f63p = {f63, f63};

    // step-invariant Kogge-Stone A-levels
    float A0 = Apair;
    float A1 = A0 * updpp<0x111, 0xf, 0xf>(1.f, A0);
    float A2 = A1 * updpp<0x112, 0xf, 0xf>(1.f, A1);
    float A3 = A2 * updpp<0x114, 0xf, 0xf>(1.f, A2);
    float A4 = A3 * updpp<0x118, 0xf, 0xf>(1.f, A3);
    float A5 = A4 * updpp<0x142, 0xa, 0xf>(1.f, A4);

    // init: alpha0 = pi0 * E(tok0)
    const float* Er0 = Es + tokL[0] * EROW;
    f32x2 aM = {pi0[m0] * Er0[m0], pi0[m1] * Er0[m1]};
    f32x2 aI = {pi0[129 + m0] * Er0[130 + m0], pi0[129 + m1] * Er0[130 + m1]};
    f32x2 a2 = {f63 * pi0[128] * Er0[128], f63 * pi0[257] * Er0[258]};

    int etot = 0;
    f32x2 part = (aM + aI) + a2;

    // E-row ping-pong register sets (X = odd steps, Y = even steps)
    f32x2 xEM, xEI, xE2, yEM, yEI, yE2;
#define REFILL(PFX, TK)                                                     \
    { const float* Er_ = Es + (TK) * EROW;                                  \
      PFX##EM = *(const f32x2*)(Er_ + m0);                                  \
      PFX##EI = *(const f32x2*)(Er_ + 130 + m0);                            \
      PFX##E2 = *(const f32x2*)(Er_ + 260); }
    REFILL(x, tokL[1]);
    REFILL(y, tokL[2]);
    int t2 = tokL[3];
    int t3 = tokL[4];

#define STEP_BODY(RES, EMr, EIr, E2r)                                       \
    {                                                                       \
        f32x2 EMv = EMr, EIv = EIr, E2v = E2r;                              \
        if (RES) {                                                          \
            float s_ = wave_sum_to63(part.x + part.y);                      \
            float stot = readlane_f(s_, 63);                                \
            int sb = __float_as_int(stot) & 0x7f800000;                     \
            etot += (sb >> 23);                                             \
            float invs = __int_as_float(0x7f000000 - sb);                   \
            f32x2 iv = {invs, invs};                                        \
            EMv *= iv; EIv *= iv; E2v *= iv;                                \
        }                                                                   \
        float aMp  = updpp<0x138, 0xf, 0xf>(0.f, aM.y);   /* wf_shr:1 */    \
        float u128 = readlane_f(a2.x, 63);                                  \
        float r0 = fmaf(aMp, cM0, aI.x * cI0);                              \
        float r1 = fmaf(aM.x, cM1, aI.y * cI1);                             \
        float B = fmaf(d1v, r0, r1);                                        \
        B = fmaf(A0, updpp<0x111, 0xf, 0xf>(0.f, B), B);                    \
        B = fmaf(A1, updpp<0x112, 0xf, 0xf>(0.f, B), B);                    \
        B = fmaf(A2, updpp<0x114, 0xf, 0xf>(0.f, B), B);                    \
        B = fmaf(A3, updpp<0x118, 0xf, 0xf>(0.f, B), B);                    \
        B = fmaf(A4, updpp<0x142, 0xa, 0xf>(0.f, B), B);                    \
        B = fmaf(A5, updpp<0x143, 0xc, 0xf>(0.f, B), B);                    \
        float G0 = updpp<0x138, 0xf, 0xf>(0.f, B);                          \
        float G1 = fmaf(d0, G0, r0);                                        \
        f32x2 Gp   = {G0, G1};                                              \
        f32x2 aMs  = {aMp, aM.x};                                           \
        f32x2 u2   = {u128, u128};                                          \
        f32x2 G2p  = {B, B};                                                \
        f32x2 aM1s = {aM.y, aM.y};                                          \
        f32x2 aI2s = {a2.y, a2.y};                                          \
        f32x2 mM = wMp * Gp + (xMAp * aMs + (xMBp * aI + u2));              \
        f32x2 mI = wIp * Gp + (xIAp * aMs + (xIBp * aI + u2));              \
        f32x2 m2 = w2p * G2p + (xA2p * aM1s + (xB2p * aI2s + u2));          \
        aM = mM * EMv;                                                      \
        aI = mI * EIv;                                                      \
        a2 = m2 * E2v * f63p;                                               \
        part = (aM + aI) + a2;                                              \
    }

    // 127 pairs: steps l = 2*it+1 (X, rescale) and l+1 (Y, no rescale)
    for (int it = 0; it < 127; ++it) {
        int l = 1 + 2 * it;
        STEP_BODY(1, xEM, xEI, xE2);
        REFILL(x, t2);
        int nt2 = tokL[(l + 4) & 255];
        STEP_BODY(0, yEM, yEI, yE2);
        REFILL(y, t3);
        int nt3 = tokL[(l + 5) & 255];
        t2 = nt2; t3 = nt3;
    }
    // final step l = 255 (X set, rescale)
    STEP_BODY(1, xEM, xEI, xE2);
#undef STEP_BODY
#undef REFILL

    float s = wave_sum_to63(part.x + part.y);
    if (lane == 63)
        out[b] = (float)(etot - 128 * 127) * 0.6931471805599453f + logf(s);
}

extern "C" void kernel_launch(void* const* d_in, const int* in_sizes, int n_in,
                              void* d_out, int out_size, void* d_ws, size_t ws_size,
                              hipStream_t stream) {
    const float* data  = (const float*)d_in[0];
    const float* z     = (const float*)d_in[1];
    const float* dec_W = (const float*)d_in[2];
    const float* dec_b = (const float*)d_in[3];
    const float* ins   = (const float*)d_in[4];
    const float* del   = (const float*)d_in[5];
    const float* invt  = (const float*)d_in[6];
    float* out = (float*)d_out;

    float* ws   = (float*)d_ws;
    float* E    = ws;
    int*   tok  = (int*)(ws + OFF_TOK);
    float* coef = ws + OFF_COEF;

    k_setup<<<EMIS_BLKS + TOK_BLKS + 1, 256, 0, stream>>>(z, dec_W, dec_b, invt,
                                                          data, ins, del, E, tok, coef);
    k_fwd<<<BB, 64, 0, stream>>>(E, tok, coef, out);
}

// Round 7
// 59.385 us; speedup vs baseline: 3.3755x; 1.0452x over previous
//
#include <hip/hip_runtime.h>
#include <math.h>

// FactorMuE: profile-HMM forward log-likelihood.
// Dims (static): M=128, Mp1=129, K=258, D=21, ZD=64, B=64, L=256, P=774.
// Reference-fidelity detail: row k=128 of the transition matrix is all
// NEG=-1e32; the reference's float32 row-lse absorbs log(258), so the
// normalized row is 0.0 -> linear outflow weight 1.0 PER DESTINATION.
#define MP1 129
#define KK  258
#define DD  21
#define ZDIM 64
#define BB  64
#define LL  256
#define EROW 260   // match m at col m (0..128), 129 pad, insert m at 130+m, 259 pad
#define ETOK 22    // 21 tokens + ones row (index 21 = missing)

// ---------------- ws layout (floats) ----------------
#define OFF_TOK  366080            // 64*22*260
#define OFF_COEF 382464
#define C_UU   0
#define C_DXM  258
#define C_DXI  516
#define C_WM   774
#define C_WI   903
#define C_DMID 1032
#define C_PI0  1160

#define EMIS_BLKS 65     // 260 waves >= 258 (c,m)-rows, one wave per row
#define TOK_BLKS  1366   // 5464 waves, 3 rows each, single iteration

typedef float f32x2 __attribute__((ext_vector_type(2)));

// -------- DPP helpers (cross-lane on the VALU pipe) --------
template <int CTRL, int RM, int BM>
__device__ __forceinline__ float updpp(float old, float src) {
    return __int_as_float(__builtin_amdgcn_update_dpp(
        __float_as_int(old), __float_as_int(src), CTRL, RM, BM, false));
}
__device__ __forceinline__ float readlane_f(float v, int lane) {
    return __int_as_float(__builtin_amdgcn_readlane(__float_as_int(v), lane));
}
__device__ __forceinline__ float wave_sum_to63(float s) {
    s += updpp<0x111, 0xf, 0xf>(0.f, s);   // row_shr:1
    s += updpp<0x112, 0xf, 0xf>(0.f, s);   // row_shr:2
    s += updpp<0x114, 0xf, 0xf>(0.f, s);   // row_shr:4
    s += updpp<0x118, 0xf, 0xf>(0.f, s);   // row_shr:8
    s += updpp<0x142, 0xa, 0xf>(0.f, s);   // row_bcast:15
    s += updpp<0x143, 0xc, 0xf>(0.f, s);   // row_bcast:31
    return s;
}

// ==================== fused setup: coef | emis | tok by block role ====================
__global__ __launch_bounds__(256) void k_setup(const float* __restrict__ z,
                                               const float* __restrict__ W,
                                               const float* __restrict__ bias,
                                               const float* __restrict__ invt,
                                               const float* __restrict__ data,
                                               const float* __restrict__ ins,
                                               const float* __restrict__ del,
                                               float* __restrict__ E,
                                               int* __restrict__ tokout,
                                               float* __restrict__ coef) {
    __shared__ float il[774], dl[774], Smid[129], Qs[130];
    int bid = blockIdx.x;
    int tid = threadIdx.x;

    if (bid >= 1 && bid <= EMIS_BLKS) {
        // ---- emission: wave = one (c,m)-row rr, lane = batch b ----
        int b  = tid & 63;
        int rr = __builtin_amdgcn_readfirstlane((bid - 1) * 4 + (tid >> 6));
        if (rr >= KK) return;
        float it = log1pf(expf(invt[0]));          // softplus
        float4 zr[16];                             // z[b] row in VGPRs
        const float4* zp = (const float4*)(z + (size_t)b * ZDIM);
        #pragma unroll
        for (int j = 0; j < 16; ++j) zr[j] = zp[j];
        const float* wb = W + (size_t)rr * DD * ZDIM;   // wave-uniform
        const float* bp = bias + rr * DD;
        float acc[DD];
        #pragma unroll
        for (int d = 0; d < DD; ++d) {
            const float4* wp = (const float4*)(wb + d * ZDIM);
            float a = bp[d];
            #pragma unroll
            for (int j = 0; j < 16; ++j) {
                float4 w4 = wp[j];
                a += zr[j].x * w4.x + zr[j].y * w4.y + zr[j].z * w4.z + zr[j].w * w4.w;
            }
            acc[d] = a * it;
        }
        float mx = acc[0];
        #pragma unroll
        for (int d = 1; d < DD; ++d) mx = fmaxf(mx, acc[d]);
        float s = 0.f;
        #pragma unroll
        for (int d = 0; d < DD; ++d) { acc[d] = expf(acc[d] - mx); s += acc[d]; }
        float inv = 1.0f / s;
        float* Eb = E + (size_t)b * ETOK * EROW;
        int col = (rr < MP1) ? rr : (rr + 1);      // insert m -> 130+m
        #pragma unroll
        for (int d = 0; d < DD; ++d) Eb[d * EROW + col] = acc[d] * inv;
        Eb[DD * EROW + col] = 1.0f;                // ones row (missing token)
        return;
    }
    if (bid > EMIS_BLKS) {
        // ---- token extraction via ballot: 3 rows per wave, one iteration ----
        int wid  = (bid - 1 - EMIS_BLKS) * 4 + (tid >> 6);
        int lane = tid & 63;
        int r3   = lane / 21;                            // 0..3 (lane 63 idle)
        int d    = lane - r3 * 21;
        int row  = wid * 3 + r3;
        float v = 0.f;
        if (r3 < 3 && row < BB * LL) v = data[(size_t)row * DD + d];
        unsigned long long m = __ballot(v > 0.5f);
        if (r3 < 3 && d == 0 && row < BB * LL) {
            unsigned long long slice = (m >> (21 * r3)) & 0x1FFFFFULL;
            tokout[row] = slice ? (int)__builtin_ctzll(slice) : DD;
        }
        return;
    }
    // ---- bid 0: transition coefficients (O(1) per row via suffix-LSE) ----
    int t = tid;
    for (int p = t; p < 387; p += 256) {
        float x0 = ins[2 * p], x1 = ins[2 * p + 1];
        float mx = fmaxf(x0, x1);
        float ls = mx + logf(expf(x0 - mx) + expf(x1 - mx));
        il[2 * p] = x0 - ls; il[2 * p + 1] = x1 - ls;
        float y0 = del[2 * p], y1 = del[2 * p + 1];
        float my = fmaxf(y0, y1);
        float lt = my + logf(expf(y0 - my) + expf(y1 - my));
        dl[2 * p] = y0 - lt; dl[2 * p + 1] = y1 - lt;
    }
    __syncthreads();
    if (t < 64) {   // Smid prefix sum, wave 0
        int mmA = 1 + 2 * t, mmB = 2 + 2 * t;
        float xA = il[(mmA * 3 + 2) * 2 + 0] + dl[(mmA * 3 + 2) * 2 + 1];
        float xB = il[(mmB * 3 + 2) * 2 + 0] + dl[(mmB * 3 + 2) * 2 + 1];
        float sc = xA + xB;
        #pragma unroll
        for (int off = 1; off < 64; off <<= 1) {
            float vv = __shfl_up(sc, off);
            if (t >= off) sc += vv;
        }
        Smid[mmB] = sc;
        Smid[mmA] = sc - xB;
        if (t == 0) Smid[0] = 0.f;
    }
    __syncthreads();
    if (t < 64) {
        // suffix-LSE over P[mp] = Smid[mp-1] + LSE(ilM+dlM, ilI), mp=1..128.
        int mpA = 128 - 2 * t, mpB = 127 - 2 * t;
        float aM_ = il[(mpA * 3 + 2) * 2 + 0] + dl[(mpA * 3 + 2) * 2 + 0];
        float aI_ = il[(mpA * 3 + 2) * 2 + 1];
        float mA = fmaxf(aM_, aI_);
        float pA = Smid[mpA - 1] + mA + logf(expf(aM_ - mA) + expf(aI_ - mA));
        float bM_ = il[(mpB * 3 + 2) * 2 + 0] + dl[(mpB * 3 + 2) * 2 + 0];
        float bI_ = il[(mpB * 3 + 2) * 2 + 1];
        float mB = fmaxf(bM_, bI_);
        float pB = Smid[mpB - 1] + mB + logf(expf(bM_ - mB) + expf(bI_ - mB));
        float cm = fmaxf(pA, pB);
        float cs = expf(pA - cm) + expf(pB - cm);
        #pragma unroll
        for (int off = 1; off < 64; off <<= 1) {
            float om = __shfl_up(cm, off);
            float os = __shfl_up(cs, off);
            if (t >= off) {
                float M = fmaxf(cm, om);
                cs = cs * expf(cm - M) + os * expf(om - M);
                cm = M;
            }
        }
        Qs[mpB] = cm + logf(cs);
        float em = __shfl_up(cm, 1), es = __shfl_up(cs, 1);
        if (t == 0) Qs[128] = pA;
        else {
            float M = fmaxf(em, pA);
            Qs[mpA] = M + logf(es * expf(em - M) + expf(pA - M));
        }
        if (t == 0) Qs[129] = -1e30f;
    }
    __syncthreads();
    float* uu  = coef + C_UU;
    float* dxM = coef + C_DXM;
    float* dxI = coef + C_DXI;
    float* wM  = coef + C_WM;
    float* wI  = coef + C_WI;
    float* dmd = coef + C_DMID;
    float* pi0 = coef + C_PI0;
    for (int k = t; k < KK; k += 256) {
        if (k == 128) { uu[k] = 0.f; dxM[k] = 0.f; dxI[k] = 0.f; continue; }
        int g  = (k < MP1) ? 0 : 1;
        int n0 = g ? (k - MP1) : (k + 1);
        float i0 = il[(n0 * 3 + g) * 2 + 0], i1 = il[(n0 * 3 + g) * 2 + 1];
        float e0 = dl[(n0 * 3 + g) * 2 + 0], e1 = dl[(n0 * 3 + g) * 2 + 1];
        float diagM = i0 + e0;
        float diagI = i1;
        float src   = i0 + e1;
        float tail  = src - Smid[n0] + Qs[n0 + 1];
        float M3 = fmaxf(fmaxf(diagM, diagI), tail);
        float ssum = expf(diagM - M3) + expf(diagI - M3) + expf(tail - M3);
        float lse = M3 + logf(ssum);
        uu[k]  = expf(src - lse);
        dxM[k] = expf(diagM - lse);
        dxI[k] = expf(diagI - lse);
    }
    for (int mp = t; mp < MP1; mp += 256) {
        wM[mp] = expf(il[(mp * 3 + 2) * 2 + 0] + dl[(mp * 3 + 2) * 2 + 0]);
        wI[mp] = expf(il[(mp * 3 + 2) * 2 + 1]);
    }
    for (int tt = t; tt < 128; tt += 256)
        dmd[tt] = (tt == 0) ? 1.f : expf(il[(tt * 3 + 2) * 2 + 0] + dl[(tt * 3 + 2) * 2 + 1]);
    __syncthreads();
    {   // pi0: O(1) per state via Qs
        float i00 = il[0], i01 = il[1], d00 = dl[0], d01 = dl[1];
        float a00 = i00 + d00, a0129 = i01;
        float tail0 = i00 + d01 + Qs[1];
        float M3 = fmaxf(fmaxf(a00, a0129), tail0);
        float lse0 = M3 + logf(expf(a00 - M3) + expf(a0129 - M3) + expf(tail0 - M3));
        for (int kp = t; kp < KK; kp += 256) {
            int gp = (kp >= MP1);
            int mp = gp ? (kp - MP1) : kp;
            float v;
            if (mp == 0) v = gp ? a0129 : a00;
            else v = i00 + d01 + Smid[mp - 1] +
                     (gp ? il[(mp * 3 + 2) * 2 + 1]
                         : il[(mp * 3 + 2) * 2 + 0] + dl[(mp * 3 + 2) * 2 + 0]);
            pi0[kp] = expf(v - lse0);
        }
    }
}

// ==================== forward scan: 1 wave/batch, transposed-E b128 refills ====================
__global__ __launch_bounds__(64) void k_fwd(const float* __restrict__ Eg,
                                            const int* __restrict__ tokg,
                                            const float* __restrict__ coef,
                                            float* __restrict__ out) {
    const float* uu  = coef + C_UU;
    const float* dxM = coef + C_DXM;
    const float* dxI = coef + C_DXI;
    const float* wMg = coef + C_WM;
    const float* wIg = coef + C_WI;
    const float* dmd = coef + C_DMID;
    const float* pi0 = coef + C_PI0;
    __shared__ float Eo[ETOK * EROW];      // staging copy of E[b]
    __shared__ float ETL[ETOK * 64 * 4];   // [tok][lane][{EMm0,EMm1,EIm0,EIm1}]
    __shared__ float E2L[ETOK * 2];        // [tok][{E(match128), E(insert128)}]
    int lane = threadIdx.x;
    int b = blockIdx.x;
    const float4* s4 = (const float4*)(Eg + (size_t)b * ETOK * EROW);
    float4* d4 = (float4*)Eo;
    for (int i = lane; i < ETOK * EROW / 4; i += 64) d4[i] = s4[i];
    int4 tkv = ((const int4*)(tokg + b * LL))[lane];   // tokens 4*lane .. 4*lane+3
    __syncthreads();
    // transpose: each lane's 4 per-step values contiguous (one b128 per refill)
    for (int d = 0; d < ETOK; ++d) {
        const float* r = Eo + d * EROW;
        f32x2 em = *(const f32x2*)(r + 2 * lane);
        f32x2 ei = *(const f32x2*)(r + 130 + 2 * lane);
        float4 v4 = {em.x, em.y, ei.x, ei.y};
        *(float4*)(ETL + (d * 64 + lane) * 4) = v4;
    }
    if (lane < ETOK) {
        E2L[lane * 2 + 0] = Eo[lane * EROW + 128];
        E2L[lane * 2 + 1] = Eo[lane * EROW + 258];
    }
    __syncthreads();

    int m0 = 2 * lane, m1 = 2 * lane + 1;
    bool L0 = (lane == 0), L63 = (lane == 63);
    float f63 = L63 ? 1.f : 0.f;
    float cM0 = L0 ? 0.f : uu[m0 - 1];
    float cI0 = uu[129 + m0];
    float cM1 = uu[m0];
    float cI1 = uu[129 + m1];
    float d0 = dmd[m0], d1v = dmd[m1];
    float Apair = d0 * d1v;
    f32x2 wMp  = {wMg[m0], wMg[m1]};
    f32x2 wIp  = {wIg[m0], wIg[m1]};
    f32x2 xMAp = {L0 ? 0.f : dxM[m0 - 1], dxM[m0]};
    f32x2 xIAp = {L0 ? 0.f : dxI[m0 - 1], dxI[m0]};
    f32x2 xMBp = {dxM[129 + m0], dxM[129 + m1]};
    f32x2 xIBp = {dxI[129 + m0], dxI[129 + m1]};
    f32x2 w2p  = {L63 ? wMg[128] : 0.f, L63 ? wIg[128] : 0.f};
    f32x2 xA2p = {L63 ? dxM[127] : 0.f, L63 ? dxI[127] : 0.f};
    f32x2 xB2p = {L63 ? dxM[257] : 0.f, L63 ? dxI[257] : 0.f};
    f32x2 f63p = {f63, f63};

    // step-invariant Kogge-Stone A-levels
    float A0 = Apair;
    float A1 = A0 * updpp<0x111, 0xf, 0xf>(1.f, A0);
    float A2 = A1 * updpp<0x112, 0xf, 0xf>(1.f, A1);
    float A3 = A2 * updpp<0x114, 0xf, 0xf>(1.f, A2);
    float A4 = A3 * updpp<0x118, 0xf, 0xf>(1.f, A3);
    float A5 = A4 * updpp<0x142, 0xa, 0xf>(1.f, A4);

    // init: alpha0 = pi0 * E(tok0)
    int tok0 = __builtin_amdgcn_readlane(tkv.x, 0);
    float4 q0 = *(const float4*)(ETL + (tok0 * 64 + lane) * 4);
    f32x2 e20 = *(const f32x2*)(E2L + tok0 * 2);
    f32x2 aM = {pi0[m0] * q0.x, pi0[m1] * q0.y};
    f32x2 aI = {pi0[129 + m0] * q0.z, pi0[129 + m1] * q0.w};
    f32x2 a2 = {f63 * pi0[128] * e20.x, f63 * pi0[257] * e20.y};

    int etot = 0;
    f32x2 part = (aM + aI) + a2;

    // 4 rotating E buffers (steps 4it+1..4it+4), refilled 4 steps ahead
    float4 q1, q2, q3, q4;
    f32x2 e21, e22, e23, e24;
#define LOADR(QN, EN, TN)                                                    \
    { int tn_ = (TN);                                                        \
      QN = *(const float4*)(ETL + (tn_ * 64 + lane) * 4);                    \
      EN = *(const f32x2*)(E2L + tn_ * 2); }
    LOADR(q1, e21, __builtin_amdgcn_readlane(tkv.y, 0));   // step 1
    LOADR(q2, e22, __builtin_amdgcn_readlane(tkv.z, 0));   // step 2
    LOADR(q3, e23, __builtin_amdgcn_readlane(tkv.w, 0));   // step 3
    LOADR(q4, e24, __builtin_amdgcn_readlane(tkv.x, 1));   // step 4

#define STEP_BODY(RES, Qr, E2r)                                              \
    {                                                                        \
        f32x2 EMv = {Qr.x, Qr.y};                                            \
        f32x2 EIv = {Qr.z, Qr.w};                                            \
        f32x2 E2v = E2r;                                                     \
        if (RES) {                                                           \
            float s_ = wave_sum_to63(part.x + part.y);                       \
            float stot = readlane_f(s_, 63);                                 \
            int sb = __float_as_int(stot) & 0x7f800000;                      \
            etot += (sb >> 23);                                              \
            float invs = __int_as_float(0x7f000000 - sb);                    \
            f32x2 iv = {invs, invs};                                         \
            EMv *= iv; EIv *= iv; E2v *= iv;                                 \
        }                                                                    \
        float aMp  = updpp<0x138, 0xf, 0xf>(0.f, aM.y);   /* wf_shr:1 */     \
        float u128 = readlane_f(a2.x, 63);                                   \
        float r0 = fmaf(aMp, cM0, aI.x * cI0);                               \
        float r1 = fmaf(aM.x, cM1, aI.y * cI1);                              \
        float B = fmaf(d1v, r0, r1);                                         \
        B = fmaf(A0, updpp<0x111, 0xf, 0xf>(0.f, B), B);                     \
        B = fmaf(A1, updpp<0x112, 0xf, 0xf>(0.f, B), B);                     \
        B = fmaf(A2, updpp<0x114, 0xf, 0xf>(0.f, B), B);                     \
        B = fmaf(A3, updpp<0x118, 0xf, 0xf>(0.f, B), B);                     \
        B = fmaf(A4, updpp<0x142, 0xa, 0xf>(0.f, B), B);                     \
        B = fmaf(A5, updpp<0x143, 0xc, 0xf>(0.f, B), B);                     \
        float G0 = updpp<0x138, 0xf, 0xf>(0.f, B);                           \
        float G1 = fmaf(d0, G0, r0);                                         \
        f32x2 Gp   = {G0, G1};                                               \
        f32x2 aMs  = {aMp, aM.x};                                            \
        f32x2 u2   = {u128, u128};                                           \
        f32x2 G2p  = {B, B};                                                 \
        f32x2 aM1s = {aM.y, aM.y};                                           \
        f32x2 aI2s = {a2.y, a2.y};                                           \
        f32x2 mM = wMp * Gp + (xMAp * aMs + (xMBp * aI + u2));               \
        f32x2 mI = wIp * Gp + (xIAp * aMs + (xIBp * aI + u2));               \
        f32x2 m2 = w2p * G2p + (xA2p * aM1s + (xB2p * aI2s + u2));           \
        aM = mM * EMv;                                                       \
        aI = mI * EIv;                                                       \
        a2 = m2 * E2v * f63p;                                                \
        part = (aM + aI) + a2;                                               \
    }

    // 63 iterations of 4 steps: l = 4it+1 .. 4it+4 (rescale on first of each 4)
    for (int it = 0; it < 63; ++it) {
        STEP_BODY(1, q1, e21);
        LOADR(q1, e21, __builtin_amdgcn_readlane(tkv.y, it + 1));   // step 4it+5
        STEP_BODY(0, q2, e22);
        LOADR(q2, e22, __builtin_amdgcn_readlane(tkv.z, it + 1));   // step 4it+6
        STEP_BODY(0, q3, e23);
        LOADR(q3, e23, __builtin_amdgcn_readlane(tkv.w, it + 1));   // step 4it+7
        STEP_BODY(0, q4, e24);
        int it2 = (it + 2 < 64) ? (it + 2) : 63;                    // clamp (unused tail)
        LOADR(q4, e24, __builtin_amdgcn_readlane(tkv.x, it2));      // step 4it+8
    }
    // epilogue: steps 253 (rescale), 254, 255
    STEP_BODY(1, q1, e21);
    STEP_BODY(0, q2, e22);
    STEP_BODY(0, q3, e23);
#undef STEP_BODY
#undef LOADR

    float s = wave_sum_to63(part.x + part.y);
    if (lane == 63)
        out[b] = (float)(etot - 64 * 127) * 0.6931471805599453f + logf(s);
}

extern "C" void kernel_launch(void* const* d_in, const int* in_sizes, int n_in,
                              void* d_out, int out_size, void* d_ws, size_t ws_size,
                              hipStream_t stream) {
    const float* data  = (const float*)d_in[0];
    const float* z     = (const float*)d_in[1];
    const float* dec_W = (const float*)d_in[2];
    const float* dec_b = (const float*)d_in[3];
    const float* ins   = (const float*)d_in[4];
    const float* del   = (const float*)d_in[5];
    const float* invt  = (const float*)d_in[6];
    float* out = (float*)d_out;

    float* ws   = (float*)d_ws;
    float* E    = ws;
    int*   tok  = (int*)(ws + OFF_TOK);
    float* coef = ws + OFF_COEF;

    k_setup<<<1 + EMIS_BLKS + TOK_BLKS, 256, 0, stream>>>(z, dec_W, dec_b, invt,
                                                          data, ins, del, E, tok, coef);
    k_fwd<<<BB, 64, 0, stream>>>(E, tok, coef, out);
}

// Round 8
// 54.650 us; speedup vs baseline: 3.6680x; 1.0866x over previous
//
#include <hip/hip_runtime.h>
#include <math.h>

// FactorMuE: profile-HMM forward log-likelihood.
// Dims (static): M=128, Mp1=129, K=258, D=21, ZD=64, B=64, L=256, P=774.
// Reference-fidelity detail: row k=128 of the transition matrix is all
// NEG=-1e32; the reference's float32 row-lse absorbs log(258), so the
// normalized row is 0.0 -> linear outflow weight 1.0 PER DESTINATION.
#define MP1 129
#define KK  258
#define DD  21
#define ZDIM 64
#define BB  64
#define LL  256
#define EROW 260   // match m at col m (0..128), 129 pad, insert m at 130+m, 259 pad
#define ETOK 22    // 21 tokens + ones row (index 21 = missing)

// ---------------- ws layout (floats) ----------------
#define OFF_TOK  366080            // 64*22*260
#define OFF_COEF 382464
#define C_UU   0
#define C_DXM  258
#define C_DXI  516
#define C_WM   774
#define C_WI   903
#define C_DMID 1032
#define C_PI0  1160

#define EMIS_BLKS 65     // 260 waves >= 258 (c,m)-rows, one wave per row
#define TOK_BLKS  1366   // 5464 waves, 3 rows each, single iteration

typedef float f32x2 __attribute__((ext_vector_type(2)));

// -------- DPP helpers (cross-lane on the VALU pipe) --------
template <int CTRL, int RM, int BM>
__device__ __forceinline__ float updpp(float old, float src) {
    return __int_as_float(__builtin_amdgcn_update_dpp(
        __float_as_int(old), __float_as_int(src), CTRL, RM, BM, false));
}
__device__ __forceinline__ float readlane_f(float v, int lane) {
    return __int_as_float(__builtin_amdgcn_readlane(__float_as_int(v), lane));
}
__device__ __forceinline__ float wave_sum_to63(float s) {
    s += updpp<0x111, 0xf, 0xf>(0.f, s);   // row_shr:1
    s += updpp<0x112, 0xf, 0xf>(0.f, s);   // row_shr:2
    s += updpp<0x114, 0xf, 0xf>(0.f, s);   // row_shr:4
    s += updpp<0x118, 0xf, 0xf>(0.f, s);   // row_shr:8
    s += updpp<0x142, 0xa, 0xf>(0.f, s);   // row_bcast:15
    s += updpp<0x143, 0xc, 0xf>(0.f, s);   // row_bcast:31
    return s;
}

// ==================== fused setup: coef | emis | tok by block role ====================
__global__ __launch_bounds__(256, 1) void k_setup(const float* __restrict__ z,
                                                  const float* __restrict__ W,
                                                  const float* __restrict__ bias,
                                                  const float* __restrict__ invt,
                                                  const float* __restrict__ data,
                                                  const float* __restrict__ ins,
                                                  const float* __restrict__ del,
                                                  float* __restrict__ E,
                                                  int* __restrict__ tokout,
                                                  float* __restrict__ coef) {
    __shared__ float il[774], dl[774], Smid[129], Qs[130];
    int bid = blockIdx.x;
    int tid = threadIdx.x;

    if (bid >= 1 && bid <= EMIS_BLKS) {
        // ---- emission: wave = one (c,m)-row rr, lane = batch b.
        // Chunked z-dot: only 16 z floats live at once (no spill; was the
        // r7 regression -- zr[16]=64 VGPRs spilled under a 56-reg budget).
        int b  = tid & 63;
        int rr = __builtin_amdgcn_readfirstlane((bid - 1) * 4 + (tid >> 6));
        if (rr >= KK) return;
        float it = log1pf(expf(invt[0]));          // softplus
        const float* wb = W + (size_t)rr * DD * ZDIM;   // wave-uniform
        const float* bp = bias + rr * DD;
        float acc[DD];
        #pragma unroll
        for (int d = 0; d < DD; ++d) acc[d] = bp[d];
        const float4* zp = (const float4*)(z + (size_t)b * ZDIM);
        #pragma unroll
        for (int c = 0; c < 4; ++c) {              // 4 chunks x 16 floats
            float4 za = zp[4 * c + 0], zb = zp[4 * c + 1];
            float4 zc = zp[4 * c + 2], zd = zp[4 * c + 3];
            #pragma unroll
            for (int d = 0; d < DD; ++d) {
                const float4* wp = (const float4*)(wb + (size_t)d * ZDIM + 16 * c);
                float4 wa = wp[0], wv = wp[1], wc = wp[2], wd = wp[3];
                float a = acc[d];
                a = fmaf(za.x, wa.x, a); a = fmaf(za.y, wa.y, a);
                a = fmaf(za.z, wa.z, a); a = fmaf(za.w, wa.w, a);
                a = fmaf(zb.x, wv.x, a); a = fmaf(zb.y, wv.y, a);
                a = fmaf(zb.z, wv.z, a); a = fmaf(zb.w, wv.w, a);
                a = fmaf(zc.x, wc.x, a); a = fmaf(zc.y, wc.y, a);
                a = fmaf(zc.z, wc.z, a); a = fmaf(zc.w, wc.w, a);
                a = fmaf(zd.x, wd.x, a); a = fmaf(zd.y, wd.y, a);
                a = fmaf(zd.z, wd.z, a); a = fmaf(zd.w, wd.w, a);
                acc[d] = a;
            }
        }
        float mx = acc[0] * it;
        #pragma unroll
        for (int d = 0; d < DD; ++d) { acc[d] *= it; mx = fmaxf(mx, acc[d]); }
        float s = 0.f;
        #pragma unroll
        for (int d = 0; d < DD; ++d) { acc[d] = expf(acc[d] - mx); s += acc[d]; }
        float inv = 1.0f / s;
        float* Eb = E + (size_t)b * ETOK * EROW;
        int col = (rr < MP1) ? rr : (rr + 1);      // insert m -> 130+m
        #pragma unroll
        for (int d = 0; d < DD; ++d) Eb[d * EROW + col] = acc[d] * inv;
        Eb[DD * EROW + col] = 1.0f;                // ones row (missing token)
        return;
    }
    if (bid > EMIS_BLKS) {
        // ---- token extraction via ballot: 3 rows per wave, one iteration ----
        int wid  = (bid - 1 - EMIS_BLKS) * 4 + (tid >> 6);
        int lane = tid & 63;
        int r3   = lane / 21;                            // 0..3 (lane 63 idle)
        int d    = lane - r3 * 21;
        int row  = wid * 3 + r3;
        float v = 0.f;
        if (r3 < 3 && row < BB * LL) v = data[(size_t)row * DD + d];
        unsigned long long m = __ballot(v > 0.5f);
        if (r3 < 3 && d == 0 && row < BB * LL) {
            unsigned long long slice = (m >> (21 * r3)) & 0x1FFFFFULL;
            tokout[row] = slice ? (int)__builtin_ctzll(slice) : DD;
        }
        return;
    }
    // ---- bid 0: transition coefficients (O(1) per row via suffix-LSE) ----
    int t = tid;
    for (int p = t; p < 387; p += 256) {
        float x0 = ins[2 * p], x1 = ins[2 * p + 1];
        float mx = fmaxf(x0, x1);
        float ls = mx + logf(expf(x0 - mx) + expf(x1 - mx));
        il[2 * p] = x0 - ls; il[2 * p + 1] = x1 - ls;
        float y0 = del[2 * p], y1 = del[2 * p + 1];
        float my = fmaxf(y0, y1);
        float lt = my + logf(expf(y0 - my) + expf(y1 - my));
        dl[2 * p] = y0 - lt; dl[2 * p + 1] = y1 - lt;
    }
    __syncthreads();
    if (t < 64) {   // Smid prefix sum, wave 0
        int mmA = 1 + 2 * t, mmB = 2 + 2 * t;
        float xA = il[(mmA * 3 + 2) * 2 + 0] + dl[(mmA * 3 + 2) * 2 + 1];
        float xB = il[(mmB * 3 + 2) * 2 + 0] + dl[(mmB * 3 + 2) * 2 + 1];
        float sc = xA + xB;
        #pragma unroll
        for (int off = 1; off < 64; off <<= 1) {
            float vv = __shfl_up(sc, off);
            if (t >= off) sc += vv;
        }
        Smid[mmB] = sc;
        Smid[mmA] = sc - xB;
        if (t == 0) Smid[0] = 0.f;
    }
    __syncthreads();
    if (t < 64) {
        // suffix-LSE over P[mp] = Smid[mp-1] + LSE(ilM+dlM, ilI), mp=1..128.
        int mpA = 128 - 2 * t, mpB = 127 - 2 * t;
        float aM_ = il[(mpA * 3 + 2) * 2 + 0] + dl[(mpA * 3 + 2) * 2 + 0];
        float aI_ = il[(mpA * 3 + 2) * 2 + 1];
        float mA = fmaxf(aM_, aI_);
        float pA = Smid[mpA - 1] + mA + logf(expf(aM_ - mA) + expf(aI_ - mA));
        float bM_ = il[(mpB * 3 + 2) * 2 + 0] + dl[(mpB * 3 + 2) * 2 + 0];
        float bI_ = il[(mpB * 3 + 2) * 2 + 1];
        float mB = fmaxf(bM_, bI_);
        float pB = Smid[mpB - 1] + mB + logf(expf(bM_ - mB) + expf(bI_ - mB));
        float cm = fmaxf(pA, pB);
        float cs = expf(pA - cm) + expf(pB - cm);
        #pragma unroll
        for (int off = 1; off < 64; off <<= 1) {
            float om = __shfl_up(cm, off);
            float os = __shfl_up(cs, off);
            if (t >= off) {
                float M = fmaxf(cm, om);
                cs = cs * expf(cm - M) + os * expf(om - M);
                cm = M;
            }
        }
        Qs[mpB] = cm + logf(cs);
        float em = __shfl_up(cm, 1), es = __shfl_up(cs, 1);
        if (t == 0) Qs[128] = pA;
        else {
            float M = fmaxf(em, pA);
            Qs[mpA] = M + logf(es * expf(em - M) + expf(pA - M));
        }
        if (t == 0) Qs[129] = -1e30f;
    }
    __syncthreads();
    float* uu  = coef + C_UU;
    float* dxM = coef + C_DXM;
    float* dxI = coef + C_DXI;
    float* wM  = coef + C_WM;
    float* wI  = coef + C_WI;
    float* dmd = coef + C_DMID;
    float* pi0 = coef + C_PI0;
    for (int k = t; k < KK; k += 256) {
        if (k == 128) { uu[k] = 0.f; dxM[k] = 0.f; dxI[k] = 0.f; continue; }
        int g  = (k < MP1) ? 0 : 1;
        int n0 = g ? (k - MP1) : (k + 1);
        float i0 = il[(n0 * 3 + g) * 2 + 0], i1 = il[(n0 * 3 + g) * 2 + 1];
        float e0 = dl[(n0 * 3 + g) * 2 + 0], e1 = dl[(n0 * 3 + g) * 2 + 1];
        float diagM = i0 + e0;
        float diagI = i1;
        float src   = i0 + e1;
        float tail  = src - Smid[n0] + Qs[n0 + 1];
        float M3 = fmaxf(fmaxf(diagM, diagI), tail);
        float ssum = expf(diagM - M3) + expf(diagI - M3) + expf(tail - M3);
        float lse = M3 + logf(ssum);
        uu[k]  = expf(src - lse);
        dxM[k] = expf(diagM - lse);
        dxI[k] = expf(diagI - lse);
    }
    for (int mp = t; mp < MP1; mp += 256) {
        wM[mp] = expf(il[(mp * 3 + 2) * 2 + 0] + dl[(mp * 3 + 2) * 2 + 0]);
        wI[mp] = expf(il[(mp * 3 + 2) * 2 + 1]);
    }
    for (int tt = t; tt < 128; tt += 256)
        dmd[tt] = (tt == 0) ? 1.f : expf(il[(tt * 3 + 2) * 2 + 0] + dl[(tt * 3 + 2) * 2 + 1]);
    __syncthreads();
    {   // pi0: O(1) per state via Qs
        float i00 = il[0], i01 = il[1], d00 = dl[0], d01 = dl[1];
        float a00 = i00 + d00, a0129 = i01;
        float tail0 = i00 + d01 + Qs[1];
        float M3 = fmaxf(fmaxf(a00, a0129), tail0);
        float lse0 = M3 + logf(expf(a00 - M3) + expf(a0129 - M3) + expf(tail0 - M3));
        for (int kp = t; kp < KK; kp += 256) {
            int gp = (kp >= MP1);
            int mp = gp ? (kp - MP1) : kp;
            float v;
            if (mp == 0) v = gp ? a0129 : a00;
            else v = i00 + d01 + Smid[mp - 1] +
                     (gp ? il[(mp * 3 + 2) * 2 + 1]
                         : il[(mp * 3 + 2) * 2 + 0] + dl[(mp * 3 + 2) * 2 + 0]);
            pi0[kp] = expf(v - lse0);
        }
    }
}

// ==================== forward scan: 1 wave/batch, transposed-E b128 refills ====================
__global__ __launch_bounds__(64) void k_fwd(const float* __restrict__ Eg,
                                            const int* __restrict__ tokg,
                                            const float* __restrict__ coef,
                                            float* __restrict__ out) {
    const float* uu  = coef + C_UU;
    const float* dxM = coef + C_DXM;
    const float* dxI = coef + C_DXI;
    const float* wMg = coef + C_WM;
    const float* wIg = coef + C_WI;
    const float* dmd = coef + C_DMID;
    const float* pi0 = coef + C_PI0;
    __shared__ float Eo[ETOK * EROW];      // staging copy of E[b]
    __shared__ float ETL[ETOK * 64 * 4];   // [tok][lane][{EMm0,EMm1,EIm0,EIm1}]
    __shared__ float E2L[ETOK * 2];        // [tok][{E(match128), E(insert128)}]
    int lane = threadIdx.x;
    int b = blockIdx.x;
    const float4* s4 = (const float4*)(Eg + (size_t)b * ETOK * EROW);
    float4* d4 = (float4*)Eo;
    for (int i = lane; i < ETOK * EROW / 4; i += 64) d4[i] = s4[i];
    int4 tkv = ((const int4*)(tokg + b * LL))[lane];   // tokens 4*lane .. 4*lane+3
    __syncthreads();
    // transpose: each lane's 4 per-step values contiguous (one b128 per refill)
    for (int d = 0; d < ETOK; ++d) {
        const float* r = Eo + d * EROW;
        f32x2 em = *(const f32x2*)(r + 2 * lane);
        f32x2 ei = *(const f32x2*)(r + 130 + 2 * lane);
        float4 v4 = {em.x, em.y, ei.x, ei.y};
        *(float4*)(ETL + (d * 64 + lane) * 4) = v4;
    }
    if (lane < ETOK) {
        E2L[lane * 2 + 0] = Eo[lane * EROW + 128];
        E2L[lane * 2 + 1] = Eo[lane * EROW + 258];
    }
    __syncthreads();

    int m0 = 2 * lane, m1 = 2 * lane + 1;
    bool L0 = (lane == 0), L63 = (lane == 63);
    float f63 = L63 ? 1.f : 0.f;
    float cM0 = L0 ? 0.f : uu[m0 - 1];
    float cI0 = uu[129 + m0];
    float cM1 = uu[m0];
    float cI1 = uu[129 + m1];
    float d0 = dmd[m0], d1v = dmd[m1];
    float Apair = d0 * d1v;
    f32x2 wMp  = {wMg[m0], wMg[m1]};
    f32x2 wIp  = {wIg[m0], wIg[m1]};
    f32x2 xMAp = {L0 ? 0.f : dxM[m0 - 1], dxM[m0]};
    f32x2 xIAp = {L0 ? 0.f : dxI[m0 - 1], dxI[m0]};
    f32x2 xMBp = {dxM[129 + m0], dxM[129 + m1]};
    f32x2 xIBp = {dxI[129 + m0], dxI[129 + m1]};
    f32x2 w2p  = {L63 ? wMg[128] : 0.f, L63 ? wIg[128] : 0.f};
    f32x2 xA2p = {L63 ? dxM[127] : 0.f, L63 ? dxI[127] : 0.f};
    f32x2 xB2p = {L63 ? dxM[257] : 0.f, L63 ? dxI[257] : 0.f};
    f32x2 f63p = {f63, f63};

    // step-invariant Kogge-Stone A-levels
    float A0 = Apair;
    float A1 = A0 * updpp<0x111, 0xf, 0xf>(1.f, A0);
    float A2 = A1 * updpp<0x112, 0xf, 0xf>(1.f, A1);
    float A3 = A2 * updpp<0x114, 0xf, 0xf>(1.f, A2);
    float A4 = A3 * updpp<0x118, 0xf, 0xf>(1.f, A3);
    float A5 = A4 * updpp<0x142, 0xa, 0xf>(1.f, A4);
    // dmid ~ e^-10 typical -> A2 (8-term product) underflows fp32 to exact 0;
    // when a wave-wide ballot certifies A_k==0 on every lane, scan levels >=k
    // contribute fmaf(0,x,B)==B exactly -> skip them (uniform, loop-invariant).
    unsigned long long bb2 = __ballot(A2 != 0.f);
    unsigned long long bb3 = __ballot(A3 != 0.f);
    int nlev = (bb2 == 0ULL) ? 2 : ((bb3 == 0ULL) ? 3 : 6);

    // init: alpha0 = pi0 * E(tok0)
    int tok0 = __builtin_amdgcn_readlane(tkv.x, 0);
    float4 q0 = *(const float4*)(ETL + (tok0 * 64 + lane) * 4);
    f32x2 e20 = *(const f32x2*)(E2L + tok0 * 2);
    f32x2 aM = {pi0[m0] * q0.x, pi0[m1] * q0.y};
    f32x2 aI = {pi0[129 + m0] * q0.z, pi0[129 + m1] * q0.w};
    f32x2 a2 = {f63 * pi0[128] * e20.x, f63 * pi0[257] * e20.y};

    int etot = 0;
    f32x2 part = (aM + aI) + a2;

    // 4 rotating E buffers (steps 4it+1..4it+4), refilled 4 steps ahead
    float4 q1, q2, q3, q4;
    f32x2 e21, e22, e23, e24;
#define LOADR(QN, EN, TN)                                                    \
    { int tn_ = (TN);                                                        \
      QN = *(const float4*)(ETL + (tn_ * 64 + lane) * 4);                    \
      EN = *(const f32x2*)(E2L + tn_ * 2); }
    LOADR(q1, e21, __builtin_amdgcn_readlane(tkv.y, 0));   // step 1
    LOADR(q2, e22, __builtin_amdgcn_readlane(tkv.z, 0));   // step 2
    LOADR(q3, e23, __builtin_amdgcn_readlane(tkv.w, 0));   // step 3
    LOADR(q4, e24, __builtin_amdgcn_readlane(tkv.x, 1));   // step 4

#define STEP_BODY(RES, PART, NLEV, Qr, E2r)                                  \
    {                                                                        \
        f32x2 EMv = {Qr.x, Qr.y};                                            \
        f32x2 EIv = {Qr.z, Qr.w};                                            \
        f32x2 E2v = E2r;                                                     \
        if (RES) {                                                           \
            float s_ = wave_sum_to63(part.x + part.y);                       \
            float stot = readlane_f(s_, 63);                                 \
            int sb = __float_as_int(stot) & 0x7f800000;                      \
            etot += (sb >> 23);                                              \
            float invs = __int_as_float(0x7f000000 - sb);                    \
            f32x2 iv = {invs, invs};                                         \
            EMv *= iv; EIv *= iv; E2v *= iv;                                 \
        }                                                                    \
        float aMp  = updpp<0x138, 0xf, 0xf>(0.f, aM.y);   /* wf_shr:1 */     \
        float u128 = readlane_f(a2.x, 63);                                   \
        float r0 = fmaf(aMp, cM0, aI.x * cI0);                               \
        float r1 = fmaf(aM.x, cM1, aI.y * cI1);                              \
        float B = fmaf(d1v, r0, r1);                                         \
        B = fmaf(A0, updpp<0x111, 0xf, 0xf>(0.f, B), B);                     \
        B = fmaf(A1, updpp<0x112, 0xf, 0xf>(0.f, B), B);                     \
        if (NLEV > 2) B = fmaf(A2, updpp<0x114, 0xf, 0xf>(0.f, B), B);       \
        if (NLEV > 3) B = fmaf(A3, updpp<0x118, 0xf, 0xf>(0.f, B), B);       \
        if (NLEV > 4) {                                                      \
            B = fmaf(A4, updpp<0x142, 0xa, 0xf>(0.f, B), B);                 \
            B = fmaf(A5, updpp<0x143, 0xc, 0xf>(0.f, B), B);                 \
        }                                                                    \
        float G0 = updpp<0x138, 0xf, 0xf>(0.f, B);                           \
        float G1 = fmaf(d0, G0, r0);                                         \
        f32x2 Gp   = {G0, G1};                                               \
        f32x2 aMs  = {aMp, aM.x};                                            \
        f32x2 u2   = {u128, u128};                                           \
        f32x2 G2p  = {B, B};                                                 \
        f32x2 aM1s = {aM.y, aM.y};                                           \
        f32x2 aI2s = {a2.y, a2.y};                                           \
        f32x2 mM = wMp * Gp + (xMAp * aMs + (xMBp * aI + u2));               \
        f32x2 mI = wIp * Gp + (xIAp * aMs + (xIBp * aI + u2));               \
        f32x2 m2 = w2p * G2p + (xA2p * aM1s + (xB2p * aI2s + u2));           \
        aM = mM * EMv;                                                       \
        aI = mI * EIv;                                                       \
        a2 = m2 * E2v * f63p;                                                \
        if (PART) part = (aM + aI) + a2;                                     \
    }

#define RUN_SCAN(NLEV)                                                       \
    for (int it = 0; it < 63; ++it) {                                        \
        STEP_BODY(1, 0, NLEV, q1, e21);                                      \
        LOADR(q1, e21, __builtin_amdgcn_readlane(tkv.y, it + 1));            \
        STEP_BODY(0, 0, NLEV, q2, e22);                                      \
        LOADR(q2, e22, __builtin_amdgcn_readlane(tkv.z, it + 1));            \
        STEP_BODY(0, 0, NLEV, q3, e23);                                      \
        LOADR(q3, e23, __builtin_amdgcn_readlane(tkv.w, it + 1));            \
        STEP_BODY(0, 1, NLEV, q4, e24);                                      \
        int it2 = (it + 2 < 64) ? (it + 2) : 63;                             \
        LOADR(q4, e24, __builtin_amdgcn_readlane(tkv.x, it2));               \
    }                                                                        \
    STEP_BODY(1, 0, NLEV, q1, e21);                                          \
    STEP_BODY(0, 0, NLEV, q2, e22);                                          \
    STEP_BODY(0, 1, NLEV, q3, e23);

    if (nlev == 2)      { RUN_SCAN(2) }
    else if (nlev == 3) { RUN_SCAN(3) }
    else                { RUN_SCAN(6) }
#undef RUN_SCAN
#undef STEP_BODY
#undef LOADR

    float s = wave_sum_to63(part.x + part.y);
    if (lane == 63)
        out[b] = (float)(etot - 64 * 127) * 0.6931471805599453f + logf(s);
}

extern "C" void kernel_launch(void* const* d_in, const int* in_sizes, int n_in,
                              void* d_out, int out_size, void* d_ws, size_t ws_size,
                              hipStream_t stream) {
    const float* data  = (const float*)d_in[0];
    const float* z     = (const float*)d_in[1];
    const float* dec_W = (const float*)d_in[2];
    const float* dec_b = (const float*)d_in[3];
    const float* ins   = (const float*)d_in[4];
    const float* del   = (const float*)d_in[5];
    const float* invt  = (const float*)d_in[6];
    float* out = (float*)d_out;

    float* ws   = (float*)d_ws;
    float* E    = ws;
    int*   tok  = (int*)(ws + OFF_TOK);
    float* coef = ws + OFF_COEF;

    k_setup<<<1 + EMIS_BLKS + TOK_BLKS, 256, 0, stream>>>(z, dec_W, dec_b, invt,
                                                          data, ins, del, E, tok, coef);
    k_fwd<<<BB, 64, 0, stream>>>(E, tok, coef, out);
}

// Round 9
// 49.370 us; speedup vs baseline: 4.0603x; 1.1070x over previous
//
#include <hip/hip_runtime.h>
#include <math.h>

// FactorMuE: profile-HMM forward log-likelihood.
// Dims (static): M=128, Mp1=129, K=258, D=21, ZD=64, B=64, L=256, P=774.
// Reference-fidelity detail: row k=128 of the transition matrix is all
// NEG=-1e32; the reference's float32 row-lse absorbs log(258), so the
// normalized row is 0.0 -> linear outflow weight 1.0 PER DESTINATION.
#define MP1 129
#define KK  258
#define DD  21
#define ZDIM 64
#define BB  64
#define LL  256

// ---------------- ws layout (floats) ----------------
// ETg: [64][22][64][4] transposed emission table = 360448
// E2g: [64][22][2]                               = 2816
// tok: [64][256] int32                           = 16384
#define OFF_ETG  0
#define OFF_E2G  360448
#define OFF_TOK  363264
#define OFF_COEF 379648
#define C_UU   0
#define C_DXM  258
#define C_DXI  516
#define C_WM   774
#define C_WI   903
#define C_DMID 1032
#define C_PI0  1160

#define EMIS_BLKS 65     // 260 waves >= 258 (c,m)-rows, one wave per row
#define TOK_BLKS  1366   // 5464 waves, 3 rows each, single iteration

typedef float f32x2 __attribute__((ext_vector_type(2)));

// -------- DPP helpers (cross-lane on the VALU pipe) --------
template <int CTRL, int RM, int BM>
__device__ __forceinline__ float updpp(float old, float src) {
    return __int_as_float(__builtin_amdgcn_update_dpp(
        __float_as_int(old), __float_as_int(src), CTRL, RM, BM, false));
}
__device__ __forceinline__ float readlane_f(float v, int lane) {
    return __int_as_float(__builtin_amdgcn_readlane(__float_as_int(v), lane));
}
__device__ __forceinline__ float wave_sum_to63(float s) {
    s += updpp<0x111, 0xf, 0xf>(0.f, s);   // row_shr:1
    s += updpp<0x112, 0xf, 0xf>(0.f, s);   // row_shr:2
    s += updpp<0x114, 0xf, 0xf>(0.f, s);   // row_shr:4
    s += updpp<0x118, 0xf, 0xf>(0.f, s);   // row_shr:8
    s += updpp<0x142, 0xa, 0xf>(0.f, s);   // row_bcast:15
    s += updpp<0x143, 0xc, 0xf>(0.f, s);   // row_bcast:31
    return s;
}

// ==================== fused setup: coef | emis | tok by block role ====================
__global__ __launch_bounds__(256, 1) void k_setup(const float* __restrict__ z,
                                                  const float* __restrict__ W,
                                                  const float* __restrict__ bias,
                                                  const float* __restrict__ invt,
                                                  const float* __restrict__ data,
                                                  const float* __restrict__ ins,
                                                  const float* __restrict__ del,
                                                  float* __restrict__ ETg,
                                                  float* __restrict__ E2g,
                                                  int* __restrict__ tokout,
                                                  float* __restrict__ coef) {
    __shared__ float il[774], dl[774], Smid[129], Qs[130];
    int bid = blockIdx.x;
    int tid = threadIdx.x;

    if (bid >= 1 && bid <= EMIS_BLKS) {
        // ---- emission: wave = one (c,m)-row rr, lane = batch b ----
        int b  = tid & 63;
        int rr = __builtin_amdgcn_readfirstlane((bid - 1) * 4 + (tid >> 6));
        if (rr >= KK) return;
        float it = log1pf(expf(invt[0]));          // softplus
        const float* wb = W + (size_t)rr * DD * ZDIM;   // wave-uniform
        const float* bp = bias + rr * DD;
        float acc[DD];
        #pragma unroll
        for (int d = 0; d < DD; ++d) acc[d] = bp[d];
        const float4* zp = (const float4*)(z + (size_t)b * ZDIM);
        #pragma unroll
        for (int c = 0; c < 4; ++c) {              // 4 chunks x 16 floats (no spill)
            float4 za = zp[4 * c + 0], zb = zp[4 * c + 1];
            float4 zc = zp[4 * c + 2], zd = zp[4 * c + 3];
            #pragma unroll
            for (int d = 0; d < DD; ++d) {
                const float4* wp = (const float4*)(wb + (size_t)d * ZDIM + 16 * c);
                float4 wa = wp[0], wv = wp[1], wc = wp[2], wd = wp[3];
                float a = acc[d];
                a = fmaf(za.x, wa.x, a); a = fmaf(za.y, wa.y, a);
                a = fmaf(za.z, wa.z, a); a = fmaf(za.w, wa.w, a);
                a = fmaf(zb.x, wv.x, a); a = fmaf(zb.y, wv.y, a);
                a = fmaf(zb.z, wv.z, a); a = fmaf(zb.w, wv.w, a);
                a = fmaf(zc.x, wc.x, a); a = fmaf(zc.y, wc.y, a);
                a = fmaf(zc.z, wc.z, a); a = fmaf(zc.w, wc.w, a);
                a = fmaf(zd.x, wd.x, a); a = fmaf(zd.y, wd.y, a);
                a = fmaf(zd.z, wd.z, a); a = fmaf(zd.w, wd.w, a);
                acc[d] = a;
            }
        }
        float mx = acc[0] * it;
        #pragma unroll
        for (int d = 0; d < DD; ++d) { acc[d] *= it; mx = fmaxf(mx, acc[d]); }
        float s = 0.f;
        #pragma unroll
        for (int d = 0; d < DD; ++d) { acc[d] = expf(acc[d] - mx); s += acc[d]; }
        float inv = 1.0f / s;
        // write TRANSPOSED layout consumed by k_fwd without repack:
        //   match m<128 : ETg[b][d][m>>1][m&1]
        //   insert m<128: ETg[b][d][m>>1][2+(m&1)]
        //   match 128 / insert 128 -> E2g[b][d][0/1]
        if (rr == 128 || rr == 257) {
            float* eb = E2g + b * 44 + ((rr == 128) ? 0 : 1);
            #pragma unroll
            for (int d = 0; d < DD; ++d) eb[d * 2] = acc[d] * inv;
            eb[DD * 2] = 1.0f;                     // ones row (missing token)
        } else {
            bool ism = rr < 128;
            int m = ism ? rr : rr - MP1;
            int slot = (m >> 1) * 4 + (ism ? 0 : 2) + (m & 1);
            float* eb = ETg + (size_t)b * 5632 + slot;
            #pragma unroll
            for (int d = 0; d < DD; ++d) eb[d * 256] = acc[d] * inv;
            eb[DD * 256] = 1.0f;                   // ones row (missing token)
        }
        return;
    }
    if (bid > EMIS_BLKS) {
        // ---- token extraction via ballot: 3 rows per wave, one iteration ----
        int wid  = (bid - 1 - EMIS_BLKS) * 4 + (tid >> 6);
        int lane = tid & 63;
        int r3   = lane / 21;                            // 0..3 (lane 63 idle)
        int d    = lane - r3 * 21;
        int row  = wid * 3 + r3;
        float v = 0.f;
        if (r3 < 3 && row < BB * LL) v = data[(size_t)row * DD + d];
        unsigned long long m = __ballot(v > 0.5f);
        if (r3 < 3 && d == 0 && row < BB * LL) {
            unsigned long long slice = (m >> (21 * r3)) & 0x1FFFFFULL;
            tokout[row] = slice ? (int)__builtin_ctzll(slice) : DD;
        }
        return;
    }
    // ---- bid 0: transition coefficients (O(1) per row via suffix-LSE) ----
    int t = tid;
    for (int p = t; p < 387; p += 256) {
        float x0 = ins[2 * p], x1 = ins[2 * p + 1];
        float mx = fmaxf(x0, x1);
        float ls = mx + logf(expf(x0 - mx) + expf(x1 - mx));
        il[2 * p] = x0 - ls; il[2 * p + 1] = x1 - ls;
        float y0 = del[2 * p], y1 = del[2 * p + 1];
        float my = fmaxf(y0, y1);
        float lt = my + logf(expf(y0 - my) + expf(y1 - my));
        dl[2 * p] = y0 - lt; dl[2 * p + 1] = y1 - lt;
    }
    __syncthreads();
    if (t < 64) {   // Smid prefix sum, wave 0
        int mmA = 1 + 2 * t, mmB = 2 + 2 * t;
        float xA = il[(mmA * 3 + 2) * 2 + 0] + dl[(mmA * 3 + 2) * 2 + 1];
        float xB = il[(mmB * 3 + 2) * 2 + 0] + dl[(mmB * 3 + 2) * 2 + 1];
        float sc = xA + xB;
        #pragma unroll
        for (int off = 1; off < 64; off <<= 1) {
            float vv = __shfl_up(sc, off);
            if (t >= off) sc += vv;
        }
        Smid[mmB] = sc;
        Smid[mmA] = sc - xB;
        if (t == 0) Smid[0] = 0.f;
    }
    __syncthreads();
    if (t < 64) {
        // suffix-LSE over P[mp] = Smid[mp-1] + LSE(ilM+dlM, ilI), mp=1..128.
        int mpA = 128 - 2 * t, mpB = 127 - 2 * t;
        float aM_ = il[(mpA * 3 + 2) * 2 + 0] + dl[(mpA * 3 + 2) * 2 + 0];
        float aI_ = il[(mpA * 3 + 2) * 2 + 1];
        float mA = fmaxf(aM_, aI_);
        float pA = Smid[mpA - 1] + mA + logf(expf(aM_ - mA) + expf(aI_ - mA));
        float bM_ = il[(mpB * 3 + 2) * 2 + 0] + dl[(mpB * 3 + 2) * 2 + 0];
        float bI_ = il[(mpB * 3 + 2) * 2 + 1];
        float mB = fmaxf(bM_, bI_);
        float pB = Smid[mpB - 1] + mB + logf(expf(bM_ - mB) + expf(bI_ - mB));
        float cm = fmaxf(pA, pB);
        float cs = expf(pA - cm) + expf(pB - cm);
        #pragma unroll
        for (int off = 1; off < 64; off <<= 1) {
            float om = __shfl_up(cm, off);
            float os = __shfl_up(cs, off);
            if (t >= off) {
                float M = fmaxf(cm, om);
                cs = cs * expf(cm - M) + os * expf(om - M);
                cm = M;
            }
        }
        Qs[mpB] = cm + logf(cs);
        float em = __shfl_up(cm, 1), es = __shfl_up(cs, 1);
        if (t == 0) Qs[128] = pA;
        else {
            float M = fmaxf(em, pA);
            Qs[mpA] = M + logf(es * expf(em - M) + expf(pA - M));
        }
        if (t == 0) Qs[129] = -1e30f;
    }
    __syncthreads();
    float* uu  = coef + C_UU;
    float* dxM = coef + C_DXM;
    float* dxI = coef + C_DXI;
    float* wM  = coef + C_WM;
    float* wI  = coef + C_WI;
    float* dmd = coef + C_DMID;
    float* pi0 = coef + C_PI0;
    for (int k = t; k < KK; k += 256) {
        if (k == 128) { uu[k] = 0.f; dxM[k] = 0.f; dxI[k] = 0.f; continue; }
        int g  = (k < MP1) ? 0 : 1;
        int n0 = g ? (k - MP1) : (k + 1);
        float i0 = il[(n0 * 3 + g) * 2 + 0], i1 = il[(n0 * 3 + g) * 2 + 1];
        float e0 = dl[(n0 * 3 + g) * 2 + 0], e1 = dl[(n0 * 3 + g) * 2 + 1];
        float diagM = i0 + e0;
        float diagI = i1;
        float src   = i0 + e1;
        float tail  = src - Smid[n0] + Qs[n0 + 1];
        float M3 = fmaxf(fmaxf(diagM, diagI), tail);
        float ssum = expf(diagM - M3) + expf(diagI - M3) + expf(tail - M3);
        float lse = M3 + logf(ssum);
        uu[k]  = expf(src - lse);
        dxM[k] = expf(diagM - lse);
        dxI[k] = expf(diagI - lse);
    }
    for (int mp = t; mp < MP1; mp += 256) {
        wM[mp] = expf(il[(mp * 3 + 2) * 2 + 0] + dl[(mp * 3 + 2) * 2 + 0]);
        wI[mp] = expf(il[(mp * 3 + 2) * 2 + 1]);
    }
    for (int tt = t; tt < 128; tt += 256)
        dmd[tt] = (tt == 0) ? 1.f : expf(il[(tt * 3 + 2) * 2 + 0] + dl[(tt * 3 + 2) * 2 + 1]);
    __syncthreads();
    {   // pi0: O(1) per state via Qs
        float i00 = il[0], i01 = il[1], d00 = dl[0], d01 = dl[1];
        float a00 = i00 + d00, a0129 = i01;
        float tail0 = i00 + d01 + Qs[1];
        float M3 = fmaxf(fmaxf(a00, a0129), tail0);
        float lse0 = M3 + logf(expf(a00 - M3) + expf(a0129 - M3) + expf(tail0 - M3));
        for (int kp = t; kp < KK; kp += 256) {
            int gp = (kp >= MP1);
            int mp = gp ? (kp - MP1) : kp;
            float v;
            if (mp == 0) v = gp ? a0129 : a00;
            else v = i00 + d01 + Smid[mp - 1] +
                     (gp ? il[(mp * 3 + 2) * 2 + 1]
                         : il[(mp * 3 + 2) * 2 + 0] + dl[(mp * 3 + 2) * 2 + 0]);
            pi0[kp] = expf(v - lse0);
        }
    }
}

// ==================== forward scan: 1 wave/batch ====================
// Per step: ONE ds_read_b128; E2 via v_readlane from a VGPR table (no LDS);
// 1-level scan when ballot certifies Apair < 1e-3 (dropped terms <= Apair^2
// relative ~1e-6 -> <=2.5e-4 nats over 255 steps; for this data Apair~e^-20
// so FAST == EXACT below fp32 ulp).
__global__ __launch_bounds__(64) void k_fwd(const float* __restrict__ ETg,
                                            const float* __restrict__ E2g,
                                            const int* __restrict__ tokg,
                                            const float* __restrict__ coef,
                                            float* __restrict__ out) {
    const float* uu  = coef + C_UU;
    const float* dxM = coef + C_DXM;
    const float* dxI = coef + C_DXI;
    const float* wMg = coef + C_WM;
    const float* wIg = coef + C_WI;
    const float* dmd = coef + C_DMID;
    const float* pi0 = coef + C_PI0;
    __shared__ float ETLs[22 * 256];       // [tok][lane][4]
    int lane = threadIdx.x;
    int b = blockIdx.x;
    const float4* srcp = (const float4*)(ETg + (size_t)b * 5632);
    float4* dstp = (float4*)ETLs;
    for (int i = lane; i < 1408; i += 64) dstp[i] = srcp[i];
    float e2m = 0.f, e2i = 0.f;
    if (lane < 22) {
        e2m = E2g[b * 44 + lane * 2 + 0];
        e2i = E2g[b * 44 + lane * 2 + 1];
    }
    int4 tkv = ((const int4*)(tokg + b * LL))[lane];   // tokens 4*lane..4*lane+3
    __syncthreads();

    int m0 = 2 * lane, m1 = 2 * lane + 1;
    bool L0 = (lane == 0), L63 = (lane == 63);
    float f63 = L63 ? 1.f : 0.f;
    float cM0 = L0 ? 0.f : uu[m0 - 1];
    float cM1 = uu[m0];
    f32x2 cIp  = {uu[129 + m0], uu[129 + m1]};
    float d0 = dmd[m0], d1v = dmd[m1];
    float Apair = d0 * d1v;
    f32x2 wMp  = {wMg[m0], wMg[m1]};
    f32x2 wIp  = {wIg[m0], wIg[m1]};
    f32x2 xMAp = {L0 ? 0.f : dxM[m0 - 1], dxM[m0]};
    f32x2 xIAp = {L0 ? 0.f : dxI[m0 - 1], dxI[m0]};
    f32x2 xMBp = {dxM[129 + m0], dxM[129 + m1]};
    f32x2 xIBp = {dxI[129 + m0], dxI[129 + m1]};
    f32x2 w2p  = {L63 ? wMg[128] : 0.f, L63 ? wIg[128] : 0.f};
    f32x2 xA2p = {L63 ? dxM[127] : 0.f, L63 ? dxI[127] : 0.f};
    f32x2 xB2p = {L63 ? dxM[257] : 0.f, L63 ? dxI[257] : 0.f};
    f32x2 f63p = {f63, f63};

    // step-invariant Kogge-Stone A-levels
    float A0 = Apair;
    float A1 = A0 * updpp<0x111, 0xf, 0xf>(1.f, A0);
    float A2 = A1 * updpp<0x112, 0xf, 0xf>(1.f, A1);
    float A3 = A2 * updpp<0x114, 0xf, 0xf>(1.f, A2);
    float A4 = A3 * updpp<0x118, 0xf, 0xf>(1.f, A3);
    float A5 = A4 * updpp<0x142, 0xa, 0xf>(1.f, A4);
    unsigned long long bbf = __ballot(Apair >= 1.0e-3f);
    int fast = (bbf == 0ULL);

    // init: alpha0 = pi0 * E(tok0)
    int lidx = lane * 4;
    int tok0 = __builtin_amdgcn_readlane(tkv.x, 0);
    float4 q0 = *(const float4*)(ETLs + tok0 * 256 + lidx);
    f32x2 e20 = {readlane_f(e2m, tok0), readlane_f(e2i, tok0)};
    f32x2 aM = {pi0[m0] * q0.x, pi0[m1] * q0.y};
    f32x2 aI = {pi0[129 + m0] * q0.z, pi0[129 + m1] * q0.w};
    f32x2 a2 = {f63 * pi0[128] * e20.x, f63 * pi0[257] * e20.y};

    int etot = 0;
    f32x2 part = (aM + aI) + a2;

    // 4 rotating E buffers + their token ids (refilled 4 steps ahead)
    float4 q1, q2, q3, q4;
    int st1, st2, st3, st4;
#define LOADR(QN, SN, TN)                                                    \
    { int tn_ = (TN); SN = tn_;                                              \
      QN = *(const float4*)(ETLs + tn_ * 256 + lidx); }
    LOADR(q1, st1, __builtin_amdgcn_readlane(tkv.y, 0));   // step 1
    LOADR(q2, st2, __builtin_amdgcn_readlane(tkv.z, 0));   // step 2
    LOADR(q3, st3, __builtin_amdgcn_readlane(tkv.w, 0));   // step 3
    LOADR(q4, st4, __builtin_amdgcn_readlane(tkv.x, 1));   // step 4

#define STEP_BODY(RES, PART, NL, Qr, STr)                                    \
    {                                                                        \
        f32x2 EMv = {Qr.x, Qr.y};                                            \
        f32x2 EIv = {Qr.z, Qr.w};                                            \
        f32x2 E2v = {readlane_f(e2m, STr), readlane_f(e2i, STr)};            \
        if (RES) {                                                           \
            float s_ = wave_sum_to63(part.x + part.y);                       \
            float stot = readlane_f(s_, 63);                                 \
            int sb = __float_as_int(stot) & 0x7f800000;                      \
            etot += (sb >> 23);                                              \
            float invs = __int_as_float(0x7f000000 - sb);                    \
            f32x2 iv = {invs, invs};                                         \
            EMv *= iv; EIv *= iv; E2v *= iv;                                 \
        }                                                                    \
        float aMp  = updpp<0x138, 0xf, 0xf>(0.f, aM.y);   /* wf_shr:1 */     \
        float u128 = readlane_f(a2.x, 63);                                   \
        f32x2 aIc = aI * cIp;                                                \
        float r0 = fmaf(aMp, cM0, aIc.x);                                    \
        float r1 = fmaf(aM.x, cM1, aIc.y);                                   \
        float B = fmaf(d1v, r0, r1);                                         \
        B = fmaf(A0, updpp<0x111, 0xf, 0xf>(0.f, B), B);                     \
        if (NL > 1) {                                                        \
            B = fmaf(A1, updpp<0x112, 0xf, 0xf>(0.f, B), B);                 \
            B = fmaf(A2, updpp<0x114, 0xf, 0xf>(0.f, B), B);                 \
            B = fmaf(A3, updpp<0x118, 0xf, 0xf>(0.f, B), B);                 \
            B = fmaf(A4, updpp<0x142, 0xa, 0xf>(0.f, B), B);                 \
            B = fmaf(A5, updpp<0x143, 0xc, 0xf>(0.f, B), B);                 \
        }                                                                    \
        float G0 = updpp<0x138, 0xf, 0xf>(0.f, B);                           \
        float G1 = fmaf(d0, G0, r0);                                         \
        f32x2 Gp   = {G0, G1};                                               \
        f32x2 aMs  = {aMp, aM.x};                                            \
        f32x2 u2   = {u128, u128};                                           \
        f32x2 G2p  = {B, B};                                                 \
        f32x2 aM1s = {aM.y, aM.y};                                           \
        f32x2 aI2s = {a2.y, a2.y};                                           \
        f32x2 mM = wMp * Gp + (xMAp * aMs + (xMBp * aI + u2));               \
        f32x2 mI = wIp * Gp + (xIAp * aMs + (xIBp * aI + u2));               \
        f32x2 m2 = w2p * G2p + (xA2p * aM1s + (xB2p * aI2s + u2));           \
        aM = mM * EMv;                                                       \
        aI = mI * EIv;                                                       \
        a2 = m2 * E2v * f63p;                                                \
        if (PART) part = (aM + aI) + a2;                                     \
    }

#define RUN_SCAN(NL)                                                         \
    for (int it = 0; it < 63; ++it) {                                        \
        STEP_BODY(1, 0, NL, q1, st1);                                        \
        LOADR(q1, st1, __builtin_amdgcn_readlane(tkv.y, it + 1));            \
        STEP_BODY(0, 0, NL, q2, st2);                                        \
        LOADR(q2, st2, __builtin_amdgcn_readlane(tkv.z, it + 1));            \
        STEP_BODY(0, 0, NL, q3, st3);                                        \
        LOADR(q3, st3, __builtin_amdgcn_readlane(tkv.w, it + 1));            \
        STEP_BODY(0, 1, NL, q4, st4);                                        \
        int it2 = (it + 2 < 64) ? (it + 2) : 63;                             \
        LOADR(q4, st4, __builtin_amdgcn_readlane(tkv.x, it2));               \
    }                                                                        \
    STEP_BODY(1, 0, NL, q1, st1);                                            \
    STEP_BODY(0, 0, NL, q2, st2);                                            \
    STEP_BODY(0, 1, NL, q3, st3);

    if (fast) { RUN_SCAN(1) }
    else      { RUN_SCAN(6) }
#undef RUN_SCAN
#undef STEP_BODY
#undef LOADR

    float s = wave_sum_to63(part.x + part.y);
    if (lane == 63)
        out[b] = (float)(etot - 64 * 127) * 0.6931471805599453f + logf(s);
}

extern "C" void kernel_launch(void* const* d_in, const int* in_sizes, int n_in,
                              void* d_out, int out_size, void* d_ws, size_t ws_size,
                              hipStream_t stream) {
    const float* data  = (const float*)d_in[0];
    const float* z     = (const float*)d_in[1];
    const float* dec_W = (const float*)d_in[2];
    const float* dec_b = (const float*)d_in[3];
    const float* ins   = (const float*)d_in[4];
    const float* del   = (const float*)d_in[5];
    const float* invt  = (const float*)d_in[6];
    float* out = (float*)d_out;

    float* ws   = (float*)d_ws;
    float* ETg  = ws + OFF_ETG;
    float* E2g  = ws + OFF_E2G;
    int*   tok  = (int*)(ws + OFF_TOK);
    float* coef = ws + OFF_COEF;

    k_setup<<<1 + EMIS_BLKS + TOK_BLKS, 256, 0, stream>>>(z, dec_W, dec_b, invt,
                                                          data, ins, del, ETg, E2g,
                                                          tok, coef);
    k_fwd<<<BB, 64, 0, stream>>>(ETg, E2g, tok, coef, out);
}